// Round 1
// baseline (790.033 us; speedup 1.0000x reference)
//
#include <hip/hip_runtime.h>
#include <math.h>

#define NDET 256
#define NTRK 256
#define NV   512
#define PPTS 512

__device__ __forceinline__ float sigf(float x) { return 1.f / (1.f + expf(-x)); }

// ---------------------------------------------------------------------------
// PointNet: per object (512 blocks), pointwise MLP 5->64->128->64, max over pts.
// LDS-staged weights (W1,W2) + per-chunk activation tiles; W3 streamed from
// global (L1 broadcast). 4x4 register blocking in the 64->128 stage.
// Writes hout[b][0:64].
// ---------------------------------------------------------------------------
__global__ __launch_bounds__(256) void pointnet_kernel(
    const float* __restrict__ det_pts, const float* __restrict__ track_pts,
    const float* __restrict__ w1, const float* __restrict__ b1,
    const float* __restrict__ w2, const float* __restrict__ b2,
    const float* __restrict__ w3, const float* __restrict__ b3,
    float* __restrict__ hout)
{
    __shared__ __align__(16) float sW1[64][6];
    __shared__ __align__(16) float sW2[128][68];   // padded stride 68 (16B aligned, bank-spread)
    __shared__ float sB1[64];
    __shared__ float sB2[128];
    __shared__ __align__(16) float sX[160];        // 32 pts x 5
    __shared__ __align__(16) float sh1[32][68];
    __shared__ __align__(16) float sh2[32][132];

    const int t = threadIdx.x;
    const int b = blockIdx.x;
    const float* x = (b < NDET) ? (det_pts + (size_t)b * PPTS * 5)
                                : (track_pts + (size_t)(b - NDET) * PPTS * 5);

    for (int i = t; i < 320; i += 256) sW1[i / 5][i % 5] = w1[i];
    for (int i = t; i < 8192; i += 256) sW2[i >> 6][i & 63] = w2[i];
    if (t < 64) sB1[t] = b1[t];
    if (t < 128) sB2[t] = b2[t];
    __syncthreads();

    float rmax[4] = {-1e30f, -1e30f, -1e30f, -1e30f};

    for (int c = 0; c < PPTS / 32; ++c) {
        if (t < 160) sX[t] = x[c * 160 + t];
        __syncthreads();

        // ---- stage 1: h1[pt][d] = relu(x . W1row + b1), pt = t&31, d = (t>>5)*8 + j
        {
            const int pt = t & 31;
            const int d0 = (t >> 5) * 8;
            float xv[5];
#pragma unroll
            for (int k = 0; k < 5; ++k) xv[k] = sX[pt * 5 + k];
#pragma unroll
            for (int j = 0; j < 8; ++j) {
                const int d = d0 + j;
                float a = sB1[d];
#pragma unroll
                for (int k = 0; k < 5; ++k) a = fmaf(xv[k], sW1[d][k], a);
                sh1[pt][d] = fmaxf(a, 0.f);
            }
        }
        __syncthreads();

        // ---- stage 2: h2 = relu(h1 @ W2^T + b2); 4 pts x 4 dds per thread
        {
            const int q = t & 7;    // pt = q + 8*pj
            const int r = t >> 3;   // dd = r + 32*dj  (r in 0..31)
            float acc[4][4];
#pragma unroll
            for (int dj = 0; dj < 4; ++dj) {
                const float bv = sB2[r + 32 * dj];
#pragma unroll
                for (int pj = 0; pj < 4; ++pj) acc[pj][dj] = bv;
            }
            for (int k = 0; k < 64; k += 4) {
                float4 hv[4], wv[4];
#pragma unroll
                for (int pj = 0; pj < 4; ++pj) hv[pj] = *(const float4*)&sh1[q + 8 * pj][k];
#pragma unroll
                for (int dj = 0; dj < 4; ++dj) wv[dj] = *(const float4*)&sW2[r + 32 * dj][k];
#pragma unroll
                for (int pj = 0; pj < 4; ++pj) {
#pragma unroll
                    for (int dj = 0; dj < 4; ++dj) {
                        acc[pj][dj] = fmaf(hv[pj].x, wv[dj].x, acc[pj][dj]);
                        acc[pj][dj] = fmaf(hv[pj].y, wv[dj].y, acc[pj][dj]);
                        acc[pj][dj] = fmaf(hv[pj].z, wv[dj].z, acc[pj][dj]);
                        acc[pj][dj] = fmaf(hv[pj].w, wv[dj].w, acc[pj][dj]);
                    }
                }
            }
#pragma unroll
            for (int pj = 0; pj < 4; ++pj)
#pragma unroll
                for (int dj = 0; dj < 4; ++dj)
                    sh2[q + 8 * pj][r + 32 * dj] = fmaxf(acc[pj][dj], 0.f);
        }
        __syncthreads();

        // ---- stage 3: h3 = h2 @ W3^T (+b3 at end); fold into running max
        // pt = (t&15) + 16*pj (pj=0..1), dd = (t>>4) + 16*dj (dj=0..3)
        {
            const int q = t & 15;
            const int r = t >> 4;
            float acc[2][4] = {{0.f, 0.f, 0.f, 0.f}, {0.f, 0.f, 0.f, 0.f}};
            for (int k = 0; k < 128; k += 4) {
                const float4 h0 = *(const float4*)&sh2[q][k];
                const float4 h1v = *(const float4*)&sh2[q + 16][k];
#pragma unroll
                for (int dj = 0; dj < 4; ++dj) {
                    const float4 wv = *(const float4*)&w3[(r + 16 * dj) * 128 + k];
                    acc[0][dj] = fmaf(h0.x, wv.x, acc[0][dj]);
                    acc[0][dj] = fmaf(h0.y, wv.y, acc[0][dj]);
                    acc[0][dj] = fmaf(h0.z, wv.z, acc[0][dj]);
                    acc[0][dj] = fmaf(h0.w, wv.w, acc[0][dj]);
                    acc[1][dj] = fmaf(h1v.x, wv.x, acc[1][dj]);
                    acc[1][dj] = fmaf(h1v.y, wv.y, acc[1][dj]);
                    acc[1][dj] = fmaf(h1v.z, wv.z, acc[1][dj]);
                    acc[1][dj] = fmaf(h1v.w, wv.w, acc[1][dj]);
                }
            }
#pragma unroll
            for (int dj = 0; dj < 4; ++dj)
                rmax[dj] = fmaxf(rmax[dj], fmaxf(acc[0][dj], acc[1][dj]));
        }
        __syncthreads();
    }

    // reduce the point-group dimension (16 consecutive threads share a dd-set)
#pragma unroll
    for (int off = 8; off >= 1; off >>= 1) {
#pragma unroll
        for (int dj = 0; dj < 4; ++dj)
            rmax[dj] = fmaxf(rmax[dj], __shfl_xor(rmax[dj], off, 16));
    }
    if ((t & 15) == 0) {
        const int r = t >> 4;
#pragma unroll
        for (int dj = 0; dj < 4; ++dj) {
            const int d = r + 16 * dj;
            hout[b * 128 + d] = rmax[dj] + b3[d];
        }
    }
}

// ---------------------------------------------------------------------------
// det motion MLP: 9 -> 32 (relu) -> 64. One block per detection.
// Writes hout[d][64:128].
// ---------------------------------------------------------------------------
__global__ __launch_bounds__(64) void detmot_kernel(
    const float* __restrict__ det_boxes,
    const float* __restrict__ w1, const float* __restrict__ b1,
    const float* __restrict__ w2, const float* __restrict__ b2,
    float* __restrict__ hout)
{
    __shared__ float sx[9];
    __shared__ float sh[32];
    const int t = threadIdx.x, d = blockIdx.x;
    if (t < 9) sx[t] = det_boxes[d * 9 + t];
    __syncthreads();
    if (t < 32) {
        float a = b1[t];
#pragma unroll
        for (int k = 0; k < 9; ++k) a = fmaf(w1[t * 9 + k], sx[k], a);
        sh[t] = fmaxf(a, 0.f);
    }
    __syncthreads();
    float a = b2[t];
#pragma unroll
    for (int k = 0; k < 32; ++k) a = fmaf(w2[t * 32 + k], sh[k], a);
    hout[d * 128 + 64 + t] = a;
}

// ---------------------------------------------------------------------------
// Fused 2-layer LSTM over T=10. 4 tracks per block (4 x 64 threads).
// Thread u owns hidden unit u of both layers for its track.
// Writes hout[256+m][64:128] = final h of layer 1.
// ---------------------------------------------------------------------------
__global__ __launch_bounds__(256) void lstm_kernel(
    const float* __restrict__ track_boxes,
    const float* __restrict__ wih0, const float* __restrict__ whh0,
    const float* __restrict__ bih0, const float* __restrict__ bhh0,
    const float* __restrict__ wih1, const float* __restrict__ whh1,
    const float* __restrict__ bih1, const float* __restrict__ bhh1,
    float* __restrict__ hout)
{
    __shared__ __align__(16) float sh0[4][64];
    __shared__ __align__(16) float sh1[4][64];
    const int t = threadIdx.x;
    const int g = t >> 6;    // track slot in block
    const int u = t & 63;    // hidden unit
    const int m = blockIdx.x * 4 + g;

    float c0 = 0.f, c1 = 0.f, h1u = 0.f;
    sh0[g][u] = 0.f;
    sh1[g][u] = 0.f;
    __syncthreads();

    for (int s = 0; s < 10; ++s) {
        const float* xt = track_boxes + (size_t)(m * 10 + s) * 9;
        float ga[4];
        // layer 0 gates: i,f,g,o rows gi*64+u
#pragma unroll
        for (int gi = 0; gi < 4; ++gi) {
            const int row = gi * 64 + u;
            float a = bih0[row] + bhh0[row];
#pragma unroll
            for (int k = 0; k < 9; ++k) a = fmaf(wih0[row * 9 + k], xt[k], a);
            const float4* wr = (const float4*)(whh0 + row * 64);
            const float4* hr = (const float4*)sh0[g];
#pragma unroll
            for (int k = 0; k < 16; ++k) {
                const float4 w = wr[k], h = hr[k];
                a = fmaf(w.x, h.x, a); a = fmaf(w.y, h.y, a);
                a = fmaf(w.z, h.z, a); a = fmaf(w.w, h.w, a);
            }
            ga[gi] = a;
        }
        c0 = sigf(ga[1]) * c0 + sigf(ga[0]) * tanhf(ga[2]);
        const float h0u = sigf(ga[3]) * tanhf(c0);
        __syncthreads();
        sh0[g][u] = h0u;
        __syncthreads();
        // layer 1 gates: input is sh0 (this step's layer-0 h)
#pragma unroll
        for (int gi = 0; gi < 4; ++gi) {
            const int row = gi * 64 + u;
            float a = bih1[row] + bhh1[row];
            const float4* wi = (const float4*)(wih1 + row * 64);
            const float4* xr = (const float4*)sh0[g];
            const float4* wr = (const float4*)(whh1 + row * 64);
            const float4* hr = (const float4*)sh1[g];
#pragma unroll
            for (int k = 0; k < 16; ++k) {
                const float4 a1 = wi[k], b1v = xr[k];
                a = fmaf(a1.x, b1v.x, a); a = fmaf(a1.y, b1v.y, a);
                a = fmaf(a1.z, b1v.z, a); a = fmaf(a1.w, b1v.w, a);
                const float4 a2 = wr[k], b2v = hr[k];
                a = fmaf(a2.x, b2v.x, a); a = fmaf(a2.y, b2v.y, a);
                a = fmaf(a2.z, b2v.z, a); a = fmaf(a2.w, b2v.w, a);
            }
            ga[gi] = a;
        }
        c1 = sigf(ga[1]) * c1 + sigf(ga[0]) * tanhf(ga[2]);
        h1u = sigf(ga[3]) * tanhf(c1);
        __syncthreads();
        sh1[g][u] = h1u;
        __syncthreads();
    }
    hout[(size_t)(NDET + m) * 128 + 64 + u] = h1u;
}

// ---------------------------------------------------------------------------
// EdgeConv GEMMs: Th = h @ wt^T ; Ph = h @ wp^T + bp. One block per vertex.
// ---------------------------------------------------------------------------
__global__ __launch_bounds__(128) void econv_gemm_kernel(
    const float* __restrict__ hin, const float* __restrict__ wt,
    const float* __restrict__ wp, const float* __restrict__ bp,
    float* __restrict__ Th, float* __restrict__ Ph)
{
    __shared__ __align__(16) float srow[128];
    const int t = threadIdx.x, v = blockIdx.x;
    srow[t] = hin[v * 128 + t];
    __syncthreads();
    const float4* hr = (const float4*)srow;
    const float4* wtr = (const float4*)(wt + t * 128);
    const float4* wpr = (const float4*)(wp + t * 128);
    float aT = 0.f, aP = bp[t];
#pragma unroll 8
    for (int k = 0; k < 32; ++k) {
        const float4 h = hr[k];
        const float4 a = wtr[k];
        aT = fmaf(a.x, h.x, aT); aT = fmaf(a.y, h.y, aT);
        aT = fmaf(a.z, h.z, aT); aT = fmaf(a.w, h.w, aT);
        const float4 b = wpr[k];
        aP = fmaf(b.x, h.x, aP); aP = fmaf(b.y, h.y, aP);
        aP = fmaf(b.z, h.z, aP); aP = fmaf(b.w, h.w, aP);
    }
    Th[v * 128 + t] = aT;
    Ph[v * 128 + t] = aP;
}

// ---------------------------------------------------------------------------
// EdgeConv masked neighbor-max + combine + relu. One block per target vertex i.
// mask[i][j] = adj[j][i]!=0 || i==j  (source neighbors, incl. self-loop)
// out[i] = relu(max_j Th[j] - Th[i] + bt + Ph[i])
// ---------------------------------------------------------------------------
__global__ __launch_bounds__(128) void econv_max_kernel(
    const int* __restrict__ adj, const float* __restrict__ Th,
    const float* __restrict__ Ph, const float* __restrict__ bt,
    float* __restrict__ hout)
{
    __shared__ int smask[NV];
    const int t = threadIdx.x, i = blockIdx.x;
    for (int j = t; j < NV; j += 128) smask[j] = (adj[j * NV + i] != 0) || (j == i);
    __syncthreads();
    float m = -1e30f;
    for (int j = 0; j < NV; ++j) {
        if (smask[j]) m = fmaxf(m, Th[j * 128 + t]);
    }
    hout[i * 128 + t] = fmaxf(m - Th[i * 128 + t] + bt[t] + Ph[i * 128 + t], 0.f);
}

// ---------------------------------------------------------------------------
// Affinity stage 1: u = h[:256] @ er_w1^T  ([256,64])
// ---------------------------------------------------------------------------
__global__ __launch_bounds__(64) void uproj_kernel(
    const float* __restrict__ hin, const float* __restrict__ w1,
    float* __restrict__ u)
{
    __shared__ __align__(16) float srow[128];
    const int t = threadIdx.x, i = blockIdx.x;
    srow[t] = hin[i * 128 + t];
    srow[t + 64] = hin[i * 128 + 64 + t];
    __syncthreads();
    const float4* hr = (const float4*)srow;
    const float4* wr = (const float4*)(w1 + t * 128);
    float a = 0.f;
#pragma unroll 8
    for (int k = 0; k < 32; ++k) {
        const float4 h = hr[k], w = wr[k];
        a = fmaf(w.x, h.x, a); a = fmaf(w.y, h.y, a);
        a = fmaf(w.z, h.z, a); a = fmaf(w.w, h.w, a);
    }
    u[i * 64 + t] = a;
}

// ---------------------------------------------------------------------------
// Affinity stage 2: aff[i][j] = sigmoid( sum_k w2[k]*relu(u[j][k]-u[i][k]+b1[k]) + b2 )
// ---------------------------------------------------------------------------
__global__ __launch_bounds__(256) void edge_kernel(
    const float* __restrict__ u, const float* __restrict__ b1,
    const float* __restrict__ w2, const float* __restrict__ b2,
    float* __restrict__ out)
{
    __shared__ float sui[64], sw2[64], sb1[64];
    const int t = threadIdx.x, i = blockIdx.x;
    if (t < 64) { sui[t] = u[i * 64 + t]; sw2[t] = w2[t]; sb1[t] = b1[t]; }
    __syncthreads();
    const float4* ur = (const float4*)(u + t * 64);
    float a = b2[0];
#pragma unroll
    for (int k = 0; k < 16; ++k) {
        const float4 uv = ur[k];
        const int k4 = k * 4;
        a = fmaf(sw2[k4 + 0], fmaxf(uv.x - sui[k4 + 0] + sb1[k4 + 0], 0.f), a);
        a = fmaf(sw2[k4 + 1], fmaxf(uv.y - sui[k4 + 1] + sb1[k4 + 1], 0.f), a);
        a = fmaf(sw2[k4 + 2], fmaxf(uv.z - sui[k4 + 2] + sb1[k4 + 2], 0.f), a);
        a = fmaf(sw2[k4 + 3], fmaxf(uv.w - sui[k4 + 3] + sb1[k4 + 3], 0.f), a);
    }
    out[i * 256 + t] = 1.f / (1.f + expf(-a));
}

// ---------------------------------------------------------------------------
extern "C" void kernel_launch(void* const* d_in, const int* in_sizes, int n_in,
                              void* d_out, int out_size, void* d_ws, size_t ws_size,
                              hipStream_t stream)
{
    const float* det_pts     = (const float*)d_in[0];
    const float* det_boxes   = (const float*)d_in[1];
    const float* track_pts   = (const float*)d_in[2];
    const float* track_boxes = (const float*)d_in[3];
    const int*   adj         = (const int*)d_in[4];
    const float* pn_w1 = (const float*)d_in[5],  *pn_b1 = (const float*)d_in[6];
    const float* pn_w2 = (const float*)d_in[7],  *pn_b2 = (const float*)d_in[8];
    const float* pn_w3 = (const float*)d_in[9],  *pn_b3 = (const float*)d_in[10];
    const float* dm_w1 = (const float*)d_in[11], *dm_b1 = (const float*)d_in[12];
    const float* dm_w2 = (const float*)d_in[13], *dm_b2 = (const float*)d_in[14];
    const float* l0_wih = (const float*)d_in[15], *l0_whh = (const float*)d_in[16];
    const float* l0_bih = (const float*)d_in[17], *l0_bhh = (const float*)d_in[18];
    const float* l1_wih = (const float*)d_in[19], *l1_whh = (const float*)d_in[20];
    const float* l1_bih = (const float*)d_in[21], *l1_bhh = (const float*)d_in[22];
    const float* gc_wt = (const float*)d_in[23], *gc_bt = (const float*)d_in[24];
    const float* gc_wp = (const float*)d_in[25], *gc_bp = (const float*)d_in[26];
    const float* er_w1 = (const float*)d_in[27], *er_b1 = (const float*)d_in[28];
    const float* er_w2 = (const float*)d_in[29], *er_b2 = (const float*)d_in[30];
    float* out = (float*)d_out;

    float* hA = (float*)d_ws;            // [512][128]
    float* hB = hA + NV * 128;           // [512][128]
    float* Th = hB + NV * 128;           // [512][128]
    float* Ph = Th + NV * 128;           // [512][128]
    float* uu = Ph + NV * 128;           // [256][64]

    pointnet_kernel<<<NV, 256, 0, stream>>>(det_pts, track_pts,
        pn_w1, pn_b1, pn_w2, pn_b2, pn_w3, pn_b3, hA);
    detmot_kernel<<<NDET, 64, 0, stream>>>(det_boxes, dm_w1, dm_b1, dm_w2, dm_b2, hA);
    lstm_kernel<<<64, 256, 0, stream>>>(track_boxes,
        l0_wih, l0_whh, l0_bih, l0_bhh, l1_wih, l1_whh, l1_bih, l1_bhh, hA);

    float* hin = hA;
    float* hO  = hB;
    for (int k = 0; k < 4; ++k) {
        econv_gemm_kernel<<<NV, 128, 0, stream>>>(hin,
            gc_wt + (size_t)k * 128 * 128, gc_wp + (size_t)k * 128 * 128,
            gc_bp + (size_t)k * 128, Th, Ph);
        econv_max_kernel<<<NV, 128, 0, stream>>>(adj, Th, Ph,
            gc_bt + (size_t)k * 128, hO);
        float* tmp = hin; hin = hO; hO = tmp;
        if (k == 0) {
            uproj_kernel<<<NDET, 64, 0, stream>>>(hin, er_w1, uu);
            edge_kernel<<<NDET, 256, 0, stream>>>(uu, er_b1, er_w2, er_b2, out);
        }
    }
    uproj_kernel<<<NDET, 64, 0, stream>>>(hin, er_w1, uu);
    edge_kernel<<<NDET, 256, 0, stream>>>(uu, er_b1, er_w2, er_b2, out + NDET * NTRK);
}

// Round 2
// 576.218 us; speedup vs baseline: 1.3711x; 1.3711x over previous
//
#include <hip/hip_runtime.h>
#include <math.h>

#define NDET 256
#define NTRK 256
#define NV   512
#define PPTS 512

__device__ __forceinline__ float sigf(float x) { return 1.f / (1.f + expf(-x)); }

// ---------------------------------------------------------------------------
// PointNet: per object (512 blocks), pointwise MLP 5->64->128->64, max over pts.
// ---------------------------------------------------------------------------
__global__ __launch_bounds__(256) void pointnet_kernel(
    const float* __restrict__ det_pts, const float* __restrict__ track_pts,
    const float* __restrict__ w1, const float* __restrict__ b1,
    const float* __restrict__ w2, const float* __restrict__ b2,
    const float* __restrict__ w3, const float* __restrict__ b3,
    float* __restrict__ hout)
{
    __shared__ __align__(16) float sW1[64][6];
    __shared__ __align__(16) float sW2[128][68];   // padded stride 68 (16B aligned, bank-spread)
    __shared__ float sB1[64];
    __shared__ float sB2[128];
    __shared__ __align__(16) float sX[160];        // 32 pts x 5
    __shared__ __align__(16) float sh1[32][68];
    __shared__ __align__(16) float sh2[32][132];

    const int t = threadIdx.x;
    const int b = blockIdx.x;
    const float* x = (b < NDET) ? (det_pts + (size_t)b * PPTS * 5)
                                : (track_pts + (size_t)(b - NDET) * PPTS * 5);

    for (int i = t; i < 320; i += 256) sW1[i / 5][i % 5] = w1[i];
    for (int i = t; i < 8192; i += 256) sW2[i >> 6][i & 63] = w2[i];
    if (t < 64) sB1[t] = b1[t];
    if (t < 128) sB2[t] = b2[t];
    __syncthreads();

    float rmax[4] = {-1e30f, -1e30f, -1e30f, -1e30f};

    for (int c = 0; c < PPTS / 32; ++c) {
        if (t < 160) sX[t] = x[c * 160 + t];
        __syncthreads();

        // ---- stage 1: h1[pt][d] = relu(x . W1row + b1), pt = t&31, d = (t>>5)*8 + j
        {
            const int pt = t & 31;
            const int d0 = (t >> 5) * 8;
            float xv[5];
#pragma unroll
            for (int k = 0; k < 5; ++k) xv[k] = sX[pt * 5 + k];
#pragma unroll
            for (int j = 0; j < 8; ++j) {
                const int d = d0 + j;
                float a = sB1[d];
#pragma unroll
                for (int k = 0; k < 5; ++k) a = fmaf(xv[k], sW1[d][k], a);
                sh1[pt][d] = fmaxf(a, 0.f);
            }
        }
        __syncthreads();

        // ---- stage 2: h2 = relu(h1 @ W2^T + b2); 4 pts x 4 dds per thread
        {
            const int q = t & 7;    // pt = q + 8*pj
            const int r = t >> 3;   // dd = r + 32*dj  (r in 0..31)
            float acc[4][4];
#pragma unroll
            for (int dj = 0; dj < 4; ++dj) {
                const float bv = sB2[r + 32 * dj];
#pragma unroll
                for (int pj = 0; pj < 4; ++pj) acc[pj][dj] = bv;
            }
            for (int k = 0; k < 64; k += 4) {
                float4 hv[4], wv[4];
#pragma unroll
                for (int pj = 0; pj < 4; ++pj) hv[pj] = *(const float4*)&sh1[q + 8 * pj][k];
#pragma unroll
                for (int dj = 0; dj < 4; ++dj) wv[dj] = *(const float4*)&sW2[r + 32 * dj][k];
#pragma unroll
                for (int pj = 0; pj < 4; ++pj) {
#pragma unroll
                    for (int dj = 0; dj < 4; ++dj) {
                        acc[pj][dj] = fmaf(hv[pj].x, wv[dj].x, acc[pj][dj]);
                        acc[pj][dj] = fmaf(hv[pj].y, wv[dj].y, acc[pj][dj]);
                        acc[pj][dj] = fmaf(hv[pj].z, wv[dj].z, acc[pj][dj]);
                        acc[pj][dj] = fmaf(hv[pj].w, wv[dj].w, acc[pj][dj]);
                    }
                }
            }
#pragma unroll
            for (int pj = 0; pj < 4; ++pj)
#pragma unroll
                for (int dj = 0; dj < 4; ++dj)
                    sh2[q + 8 * pj][r + 32 * dj] = fmaxf(acc[pj][dj], 0.f);
        }
        __syncthreads();

        // ---- stage 3: h3 = h2 @ W3^T (+b3 at end); fold into running max
        {
            const int q = t & 15;
            const int r = t >> 4;
            float acc[2][4] = {{0.f, 0.f, 0.f, 0.f}, {0.f, 0.f, 0.f, 0.f}};
            for (int k = 0; k < 128; k += 4) {
                const float4 h0 = *(const float4*)&sh2[q][k];
                const float4 h1v = *(const float4*)&sh2[q + 16][k];
#pragma unroll
                for (int dj = 0; dj < 4; ++dj) {
                    const float4 wv = *(const float4*)&w3[(r + 16 * dj) * 128 + k];
                    acc[0][dj] = fmaf(h0.x, wv.x, acc[0][dj]);
                    acc[0][dj] = fmaf(h0.y, wv.y, acc[0][dj]);
                    acc[0][dj] = fmaf(h0.z, wv.z, acc[0][dj]);
                    acc[0][dj] = fmaf(h0.w, wv.w, acc[0][dj]);
                    acc[1][dj] = fmaf(h1v.x, wv.x, acc[1][dj]);
                    acc[1][dj] = fmaf(h1v.y, wv.y, acc[1][dj]);
                    acc[1][dj] = fmaf(h1v.z, wv.z, acc[1][dj]);
                    acc[1][dj] = fmaf(h1v.w, wv.w, acc[1][dj]);
                }
            }
#pragma unroll
            for (int dj = 0; dj < 4; ++dj)
                rmax[dj] = fmaxf(rmax[dj], fmaxf(acc[0][dj], acc[1][dj]));
        }
        __syncthreads();
    }

#pragma unroll
    for (int off = 8; off >= 1; off >>= 1) {
#pragma unroll
        for (int dj = 0; dj < 4; ++dj)
            rmax[dj] = fmaxf(rmax[dj], __shfl_xor(rmax[dj], off, 16));
    }
    if ((t & 15) == 0) {
        const int r = t >> 4;
#pragma unroll
        for (int dj = 0; dj < 4; ++dj) {
            const int d = r + 16 * dj;
            hout[b * 128 + d] = rmax[dj] + b3[d];
        }
    }
}

// ---------------------------------------------------------------------------
// det motion MLP: 9 -> 32 (relu) -> 64. One block per detection.
// ---------------------------------------------------------------------------
__global__ __launch_bounds__(64) void detmot_kernel(
    const float* __restrict__ det_boxes,
    const float* __restrict__ w1, const float* __restrict__ b1,
    const float* __restrict__ w2, const float* __restrict__ b2,
    float* __restrict__ hout)
{
    __shared__ float sx[9];
    __shared__ float sh[32];
    const int t = threadIdx.x, d = blockIdx.x;
    if (t < 9) sx[t] = det_boxes[d * 9 + t];
    __syncthreads();
    if (t < 32) {
        float a = b1[t];
#pragma unroll
        for (int k = 0; k < 9; ++k) a = fmaf(w1[t * 9 + k], sx[k], a);
        sh[t] = fmaxf(a, 0.f);
    }
    __syncthreads();
    float a = b2[t];
#pragma unroll
    for (int k = 0; k < 32; ++k) a = fmaf(w2[t * 32 + k], sh[k], a);
    hout[d * 128 + 64 + t] = a;
}

// ---------------------------------------------------------------------------
// Fused 2-layer LSTM, row-parallel. One block per track; 256 threads = one
// per gate-row. Weight rows live in REGISTERS (loaded once, ~201 VGPR;
// launch_bounds(256,1) gives the 512-reg budget). Per-step shared state (h)
// is a 64-float LDS vector read with same-address broadcast float4 loads.
// Gate exchange + cell update via LDS; c-state in threads t<64.
// ---------------------------------------------------------------------------
__global__ __launch_bounds__(256, 1) void lstm_kernel(
    const float* __restrict__ track_boxes,
    const float* __restrict__ wih0, const float* __restrict__ whh0,
    const float* __restrict__ bih0, const float* __restrict__ bhh0,
    const float* __restrict__ wih1, const float* __restrict__ whh1,
    const float* __restrict__ bih1, const float* __restrict__ bhh1,
    float* __restrict__ hout)
{
    __shared__ float sx[90];                       // 10 steps x 9
    __shared__ float sg[256];                      // gate exchange
    __shared__ __align__(16) float sh0[64];
    __shared__ __align__(16) float sh1[64];

    const int t = threadIdx.x;
    const int m = blockIdx.x;
    const int u = t & 63;

    if (t < 90) sx[t] = track_boxes[m * 90 + t];
    if (t < 64) { sh0[t] = 0.f; sh1[t] = 0.f; }

    // one-time weight-row loads into registers
    float w0[9];
#pragma unroll
    for (int k = 0; k < 9; ++k) w0[k] = wih0[t * 9 + k];
    float4 wr0[16], wi1[16], wr1[16];
    {
        const float4* p0 = (const float4*)(whh0 + t * 64);
        const float4* p1 = (const float4*)(wih1 + t * 64);
        const float4* p2 = (const float4*)(whh1 + t * 64);
#pragma unroll
        for (int k = 0; k < 16; ++k) { wr0[k] = p0[k]; wi1[k] = p1[k]; wr1[k] = p2[k]; }
    }
    const float bias0 = bih0[t] + bhh0[t];
    const float bias1 = bih1[t] + bhh1[t];

    float c0 = 0.f, c1 = 0.f, h1reg = 0.f;
    __syncthreads();

    for (int s = 0; s < 10; ++s) {
        // ---- layer 0 gate row t
        {
            float acc0 = bias0, acc1 = 0.f, acc2 = 0.f, acc3 = 0.f;
#pragma unroll
            for (int k = 0; k < 9; ++k) acc0 = fmaf(w0[k], sx[s * 9 + k], acc0);
            const float4* hv = (const float4*)sh0;
#pragma unroll
            for (int k = 0; k < 16; k += 4) {
                float4 hA = hv[k], hB = hv[k + 1], hC = hv[k + 2], hD = hv[k + 3];
                acc0 = fmaf(wr0[k].x, hA.x, acc0); acc0 = fmaf(wr0[k].y, hA.y, acc0);
                acc0 = fmaf(wr0[k].z, hA.z, acc0); acc0 = fmaf(wr0[k].w, hA.w, acc0);
                acc1 = fmaf(wr0[k+1].x, hB.x, acc1); acc1 = fmaf(wr0[k+1].y, hB.y, acc1);
                acc1 = fmaf(wr0[k+1].z, hB.z, acc1); acc1 = fmaf(wr0[k+1].w, hB.w, acc1);
                acc2 = fmaf(wr0[k+2].x, hC.x, acc2); acc2 = fmaf(wr0[k+2].y, hC.y, acc2);
                acc2 = fmaf(wr0[k+2].z, hC.z, acc2); acc2 = fmaf(wr0[k+2].w, hC.w, acc2);
                acc3 = fmaf(wr0[k+3].x, hD.x, acc3); acc3 = fmaf(wr0[k+3].y, hD.y, acc3);
                acc3 = fmaf(wr0[k+3].z, hD.z, acc3); acc3 = fmaf(wr0[k+3].w, hD.w, acc3);
            }
            sg[t] = (acc0 + acc1) + (acc2 + acc3);
        }
        __syncthreads();
        if (t < 64) {
            const float gi = sg[u], gf = sg[64 + u], gg = sg[128 + u], go = sg[192 + u];
            c0 = sigf(gf) * c0 + sigf(gi) * tanhf(gg);
            sh0[u] = sigf(go) * tanhf(c0);
        }
        __syncthreads();

        // ---- layer 1 gate row t (x = sh0, h = sh1)
        {
            float acc0 = bias1, acc1 = 0.f, acc2 = 0.f, acc3 = 0.f;
            const float4* xv = (const float4*)sh0;
            const float4* hv = (const float4*)sh1;
#pragma unroll
            for (int k = 0; k < 16; k += 4) {
                float4 xA = xv[k], xB = xv[k + 1], xC = xv[k + 2], xD = xv[k + 3];
                acc0 = fmaf(wi1[k].x, xA.x, acc0); acc0 = fmaf(wi1[k].y, xA.y, acc0);
                acc0 = fmaf(wi1[k].z, xA.z, acc0); acc0 = fmaf(wi1[k].w, xA.w, acc0);
                acc1 = fmaf(wi1[k+1].x, xB.x, acc1); acc1 = fmaf(wi1[k+1].y, xB.y, acc1);
                acc1 = fmaf(wi1[k+1].z, xB.z, acc1); acc1 = fmaf(wi1[k+1].w, xB.w, acc1);
                acc2 = fmaf(wi1[k+2].x, xC.x, acc2); acc2 = fmaf(wi1[k+2].y, xC.y, acc2);
                acc2 = fmaf(wi1[k+2].z, xC.z, acc2); acc2 = fmaf(wi1[k+2].w, xC.w, acc2);
                acc3 = fmaf(wi1[k+3].x, xD.x, acc3); acc3 = fmaf(wi1[k+3].y, xD.y, acc3);
                acc3 = fmaf(wi1[k+3].z, xD.z, acc3); acc3 = fmaf(wi1[k+3].w, xD.w, acc3);
            }
#pragma unroll
            for (int k = 0; k < 16; k += 4) {
                float4 hA = hv[k], hB = hv[k + 1], hC = hv[k + 2], hD = hv[k + 3];
                acc0 = fmaf(wr1[k].x, hA.x, acc0); acc0 = fmaf(wr1[k].y, hA.y, acc0);
                acc0 = fmaf(wr1[k].z, hA.z, acc0); acc0 = fmaf(wr1[k].w, hA.w, acc0);
                acc1 = fmaf(wr1[k+1].x, hB.x, acc1); acc1 = fmaf(wr1[k+1].y, hB.y, acc1);
                acc1 = fmaf(wr1[k+1].z, hB.z, acc1); acc1 = fmaf(wr1[k+1].w, hB.w, acc1);
                acc2 = fmaf(wr1[k+2].x, hC.x, acc2); acc2 = fmaf(wr1[k+2].y, hC.y, acc2);
                acc2 = fmaf(wr1[k+2].z, hC.z, acc2); acc2 = fmaf(wr1[k+2].w, hC.w, acc2);
                acc3 = fmaf(wr1[k+3].x, hD.x, acc3); acc3 = fmaf(wr1[k+3].y, hD.y, acc3);
                acc3 = fmaf(wr1[k+3].z, hD.z, acc3); acc3 = fmaf(wr1[k+3].w, hD.w, acc3);
            }
            sg[t] = (acc0 + acc1) + (acc2 + acc3);
        }
        __syncthreads();
        if (t < 64) {
            const float gi = sg[u], gf = sg[64 + u], gg = sg[128 + u], go = sg[192 + u];
            c1 = sigf(gf) * c1 + sigf(gi) * tanhf(gg);
            h1reg = sigf(go) * tanhf(c1);
            sh1[u] = h1reg;
        }
        __syncthreads();
    }

    if (t < 64) hout[(size_t)(NDET + m) * 128 + 64 + u] = h1reg;
}

// ---------------------------------------------------------------------------
// EdgeConv GEMMs: Th = h @ wt^T ; Ph = h @ wp^T + bp. One block per vertex.
// ---------------------------------------------------------------------------
__global__ __launch_bounds__(128) void econv_gemm_kernel(
    const float* __restrict__ hin, const float* __restrict__ wt,
    const float* __restrict__ wp, const float* __restrict__ bp,
    float* __restrict__ Th, float* __restrict__ Ph)
{
    __shared__ __align__(16) float srow[128];
    const int t = threadIdx.x, v = blockIdx.x;
    srow[t] = hin[v * 128 + t];
    __syncthreads();
    const float4* hr = (const float4*)srow;
    const float4* wtr = (const float4*)(wt + t * 128);
    const float4* wpr = (const float4*)(wp + t * 128);
    float aT = 0.f, aP = bp[t];
#pragma unroll 8
    for (int k = 0; k < 32; ++k) {
        const float4 h = hr[k];
        const float4 a = wtr[k];
        aT = fmaf(a.x, h.x, aT); aT = fmaf(a.y, h.y, aT);
        aT = fmaf(a.z, h.z, aT); aT = fmaf(a.w, h.w, aT);
        const float4 b = wpr[k];
        aP = fmaf(b.x, h.x, aP); aP = fmaf(b.y, h.y, aP);
        aP = fmaf(b.z, h.z, aP); aP = fmaf(b.w, h.w, aP);
    }
    Th[v * 128 + t] = aT;
    Ph[v * 128 + t] = aP;
}

// ---------------------------------------------------------------------------
// EdgeConv masked neighbor-max + combine + relu. One block per target vertex i.
// ---------------------------------------------------------------------------
__global__ __launch_bounds__(128) void econv_max_kernel(
    const int* __restrict__ adj, const float* __restrict__ Th,
    const float* __restrict__ Ph, const float* __restrict__ bt,
    float* __restrict__ hout)
{
    __shared__ int smask[NV];
    const int t = threadIdx.x, i = blockIdx.x;
    for (int j = t; j < NV; j += 128) smask[j] = (adj[j * NV + i] != 0) || (j == i);
    __syncthreads();
    float m = -1e30f;
    for (int j = 0; j < NV; ++j) {
        if (smask[j]) m = fmaxf(m, Th[j * 128 + t]);
    }
    hout[i * 128 + t] = fmaxf(m - Th[i * 128 + t] + bt[t] + Ph[i * 128 + t], 0.f);
}

// ---------------------------------------------------------------------------
// Affinity stage 1: u = h[:256] @ er_w1^T  ([256,64])
// ---------------------------------------------------------------------------
__global__ __launch_bounds__(64) void uproj_kernel(
    const float* __restrict__ hin, const float* __restrict__ w1,
    float* __restrict__ u)
{
    __shared__ __align__(16) float srow[128];
    const int t = threadIdx.x, i = blockIdx.x;
    srow[t] = hin[i * 128 + t];
    srow[t + 64] = hin[i * 128 + 64 + t];
    __syncthreads();
    const float4* hr = (const float4*)srow;
    const float4* wr = (const float4*)(w1 + t * 128);
    float a = 0.f;
#pragma unroll 8
    for (int k = 0; k < 32; ++k) {
        const float4 h = hr[k], w = wr[k];
        a = fmaf(w.x, h.x, a); a = fmaf(w.y, h.y, a);
        a = fmaf(w.z, h.z, a); a = fmaf(w.w, h.w, a);
    }
    u[i * 64 + t] = a;
}

// ---------------------------------------------------------------------------
// Affinity stage 2: aff[i][j] = sigmoid( sum_k w2[k]*relu(u[j][k]-u[i][k]+b1[k]) + b2 )
// ---------------------------------------------------------------------------
__global__ __launch_bounds__(256) void edge_kernel(
    const float* __restrict__ u, const float* __restrict__ b1,
    const float* __restrict__ w2, const float* __restrict__ b2,
    float* __restrict__ out)
{
    __shared__ float sui[64], sw2[64], sb1[64];
    const int t = threadIdx.x, i = blockIdx.x;
    if (t < 64) { sui[t] = u[i * 64 + t]; sw2[t] = w2[t]; sb1[t] = b1[t]; }
    __syncthreads();
    const float4* ur = (const float4*)(u + t * 64);
    float a = b2[0];
#pragma unroll
    for (int k = 0; k < 16; ++k) {
        const float4 uv = ur[k];
        const int k4 = k * 4;
        a = fmaf(sw2[k4 + 0], fmaxf(uv.x - sui[k4 + 0] + sb1[k4 + 0], 0.f), a);
        a = fmaf(sw2[k4 + 1], fmaxf(uv.y - sui[k4 + 1] + sb1[k4 + 1], 0.f), a);
        a = fmaf(sw2[k4 + 2], fmaxf(uv.z - sui[k4 + 2] + sb1[k4 + 2], 0.f), a);
        a = fmaf(sw2[k4 + 3], fmaxf(uv.w - sui[k4 + 3] + sb1[k4 + 3], 0.f), a);
    }
    out[i * 256 + t] = 1.f / (1.f + expf(-a));
}

// ---------------------------------------------------------------------------
extern "C" void kernel_launch(void* const* d_in, const int* in_sizes, int n_in,
                              void* d_out, int out_size, void* d_ws, size_t ws_size,
                              hipStream_t stream)
{
    const float* det_pts     = (const float*)d_in[0];
    const float* det_boxes   = (const float*)d_in[1];
    const float* track_pts   = (const float*)d_in[2];
    const float* track_boxes = (const float*)d_in[3];
    const int*   adj         = (const int*)d_in[4];
    const float* pn_w1 = (const float*)d_in[5],  *pn_b1 = (const float*)d_in[6];
    const float* pn_w2 = (const float*)d_in[7],  *pn_b2 = (const float*)d_in[8];
    const float* pn_w3 = (const float*)d_in[9],  *pn_b3 = (const float*)d_in[10];
    const float* dm_w1 = (const float*)d_in[11], *dm_b1 = (const float*)d_in[12];
    const float* dm_w2 = (const float*)d_in[13], *dm_b2 = (const float*)d_in[14];
    const float* l0_wih = (const float*)d_in[15], *l0_whh = (const float*)d_in[16];
    const float* l0_bih = (const float*)d_in[17], *l0_bhh = (const float*)d_in[18];
    const float* l1_wih = (const float*)d_in[19], *l1_whh = (const float*)d_in[20];
    const float* l1_bih = (const float*)d_in[21], *l1_bhh = (const float*)d_in[22];
    const float* gc_wt = (const float*)d_in[23], *gc_bt = (const float*)d_in[24];
    const float* gc_wp = (const float*)d_in[25], *gc_bp = (const float*)d_in[26];
    const float* er_w1 = (const float*)d_in[27], *er_b1 = (const float*)d_in[28];
    const float* er_w2 = (const float*)d_in[29], *er_b2 = (const float*)d_in[30];
    float* out = (float*)d_out;

    float* hA = (float*)d_ws;            // [512][128]
    float* hB = hA + NV * 128;           // [512][128]
    float* Th = hB + NV * 128;           // [512][128]
    float* Ph = Th + NV * 128;           // [512][128]
    float* uu = Ph + NV * 128;           // [256][64]

    pointnet_kernel<<<NV, 256, 0, stream>>>(det_pts, track_pts,
        pn_w1, pn_b1, pn_w2, pn_b2, pn_w3, pn_b3, hA);
    detmot_kernel<<<NDET, 64, 0, stream>>>(det_boxes, dm_w1, dm_b1, dm_w2, dm_b2, hA);
    lstm_kernel<<<NTRK, 256, 0, stream>>>(track_boxes,
        l0_wih, l0_whh, l0_bih, l0_bhh, l1_wih, l1_whh, l1_bih, l1_bhh, hA);

    float* hin = hA;
    float* hO  = hB;
    for (int k = 0; k < 4; ++k) {
        econv_gemm_kernel<<<NV, 128, 0, stream>>>(hin,
            gc_wt + (size_t)k * 128 * 128, gc_wp + (size_t)k * 128 * 128,
            gc_bp + (size_t)k * 128, Th, Ph);
        econv_max_kernel<<<NV, 128, 0, stream>>>(adj, Th, Ph,
            gc_bt + (size_t)k * 128, hO);
        float* tmp = hin; hin = hO; hO = tmp;
        if (k == 0) {
            uproj_kernel<<<NDET, 64, 0, stream>>>(hin, er_w1, uu);
            edge_kernel<<<NDET, 256, 0, stream>>>(uu, er_b1, er_w2, er_b2, out);
        }
    }
    uproj_kernel<<<NDET, 64, 0, stream>>>(hin, er_w1, uu);
    edge_kernel<<<NDET, 256, 0, stream>>>(uu, er_b1, er_w2, er_b2, out + NDET * NTRK);
}

// Round 4
// 430.259 us; speedup vs baseline: 1.8362x; 1.3392x over previous
//
#include <hip/hip_runtime.h>
#include <math.h>

#define NDET 256
#define NTRK 256
#define NV   512
#define PPTS 512

typedef short bf16x8 __attribute__((ext_vector_type(8)));
typedef float f32x4  __attribute__((ext_vector_type(4)));

__device__ __forceinline__ float sigf(float x) { return 1.f / (1.f + expf(-x)); }

__device__ __forceinline__ short f2bf(float f) {
    unsigned u = __float_as_uint(f);
    u += 0x7fffu + ((u >> 16) & 1u);          // RNE
    return (short)(u >> 16);
}
__device__ __forceinline__ unsigned pack2bf(float lo, float hi) {
    return (unsigned)(unsigned short)f2bf(lo) | ((unsigned)(unsigned short)f2bf(hi) << 16);
}

// ---------------------------------------------------------------------------
// PointNet with bf16 MFMA for the 64->128 and 128->64 stages.
// One block per object; 256 threads = 4 waves. 64-point chunks.
//  stage1 (VALU, fp32): x[64,5] @ W1^T -> relu -> bf16 h1[64][64] in LDS
//  stage2 (MFMA): h1 @ W2^T + b2 -> relu -> bf16 h2[64][128] in LDS
//  stage3 (MFMA): h2 @ W3^T -> fold into running column max
// Writes hout[b][0:64].
// ---------------------------------------------------------------------------
__global__ __launch_bounds__(256) void pointnet_kernel(
    const float* __restrict__ det_pts, const float* __restrict__ track_pts,
    const float* __restrict__ w1, const float* __restrict__ b1,
    const float* __restrict__ w2, const float* __restrict__ b2,
    const float* __restrict__ w3, const float* __restrict__ b3,
    float* __restrict__ hout)
{
    __shared__ __align__(16) short sW2[128][72];   // bf16 W2[n][k], stride 144B
    __shared__ __align__(16) short sW3[64][136];   // bf16 W3[n][k], stride 272B
    __shared__ __align__(16) short sH1[64][72];    // bf16 h1[pt][k]
    __shared__ __align__(16) short sH2[64][136];   // bf16 h2[pt][k]
    __shared__ __align__(16) float sX[320];        // 64 pts x 5
    __shared__ float sW1f[64][6];
    __shared__ float sB1[64];

    const int t  = threadIdx.x;
    const int b  = blockIdx.x;
    const int w  = t >> 6;          // wave 0..3
    const int ln = t & 15;          // lane&15
    const int kq = (t >> 4) & 3;    // lane>>4 within wave
    const float* x = (b < NDET) ? (det_pts + (size_t)b * PPTS * 5)
                                : (track_pts + (size_t)(b - NDET) * PPTS * 5);

    // ---- one-time weight staging (fp32 -> bf16 LDS)
    for (int i = t; i < 8192; i += 256) sW2[i >> 6][i & 63] = f2bf(w2[i]);
    for (int i = t; i < 8192; i += 256) sW3[i >> 7][i & 127] = f2bf(w3[i]);
    for (int i = t; i < 320; i += 256) sW1f[i / 5][i % 5] = w1[i];
    if (t < 64) sB1[t] = b1[t];
    __syncthreads();

    // ---- hoisted B-fragments (weights constant across chunks)
    bf16x8 bf2[2][2];   // stage2: wave w covers cols 32w..32w+31 (2 N-tiles)
#pragma unroll
    for (int nt = 0; nt < 2; ++nt)
#pragma unroll
        for (int Kt = 0; Kt < 2; ++Kt)
            bf2[nt][Kt] = *(const bf16x8*)&sW2[32 * w + 16 * nt + ln][kq * 8 + 32 * Kt];
    bf16x8 bf3[4];      // stage3: wave w covers cols 16w..16w+15
#pragma unroll
    for (int Kt = 0; Kt < 4; ++Kt)
        bf3[Kt] = *(const bf16x8*)&sW3[16 * w + ln][kq * 8 + 32 * Kt];
    float bn[2];
#pragma unroll
    for (int nt = 0; nt < 2; ++nt) bn[nt] = b2[32 * w + 16 * nt + ln];

    float runmax[4] = {-1e30f, -1e30f, -1e30f, -1e30f};

    const int pt = t & 63;          // stage1 point index
    for (int c = 0; c < PPTS / 64; ++c) {
        for (int i = t; i < 320; i += 256) sX[i] = x[c * 320 + i];   // FIXED: strided, covers all 320
        __syncthreads();

        // ---- stage 1: wave w computes dims 16w..16w+15 for its point
        {
            float xv[5];
#pragma unroll
            for (int k = 0; k < 5; ++k) xv[k] = sX[pt * 5 + k];
#pragma unroll
            for (int jj = 0; jj < 8; ++jj) {
                const int d0 = w * 16 + 2 * jj;
                float a0 = sB1[d0], a1 = sB1[d0 + 1];
#pragma unroll
                for (int k = 0; k < 5; ++k) {
                    a0 = fmaf(xv[k], sW1f[d0][k], a0);
                    a1 = fmaf(xv[k], sW1f[d0 + 1][k], a1);
                }
                *(unsigned*)&sH1[pt][d0] = pack2bf(fmaxf(a0, 0.f), fmaxf(a1, 0.f));
            }
        }
        __syncthreads();

        // ---- stage 2 (MFMA): h2 = relu(h1 @ W2^T + b2)
        {
            bf16x8 af[4][2];
#pragma unroll
            for (int Mt = 0; Mt < 4; ++Mt)
#pragma unroll
                for (int Kt = 0; Kt < 2; ++Kt)
                    af[Mt][Kt] = *(const bf16x8*)&sH1[16 * Mt + ln][kq * 8 + 32 * Kt];
#pragma unroll
            for (int Mt = 0; Mt < 4; ++Mt) {
#pragma unroll
                for (int nt = 0; nt < 2; ++nt) {
                    f32x4 cacc = {0.f, 0.f, 0.f, 0.f};
                    cacc = __builtin_amdgcn_mfma_f32_16x16x32_bf16(af[Mt][0], bf2[nt][0], cacc, 0, 0, 0);
                    cacc = __builtin_amdgcn_mfma_f32_16x16x32_bf16(af[Mt][1], bf2[nt][1], cacc, 0, 0, 0);
                    const int col = 32 * w + 16 * nt + ln;
#pragma unroll
                    for (int r = 0; r < 4; ++r)
                        sH2[16 * Mt + kq * 4 + r][col] = f2bf(fmaxf(cacc[r] + bn[nt], 0.f));
                }
            }
        }
        __syncthreads();

        // ---- stage 3 (MFMA): h3 = h2 @ W3^T, fold into running max
        {
#pragma unroll
            for (int Mt = 0; Mt < 4; ++Mt) {
                f32x4 cacc = {0.f, 0.f, 0.f, 0.f};
#pragma unroll
                for (int Kt = 0; Kt < 4; ++Kt) {
                    const bf16x8 a = *(const bf16x8*)&sH2[16 * Mt + ln][kq * 8 + 32 * Kt];
                    cacc = __builtin_amdgcn_mfma_f32_16x16x32_bf16(a, bf3[Kt], cacc, 0, 0, 0);
                }
#pragma unroll
                for (int r = 0; r < 4; ++r) runmax[r] = fmaxf(runmax[r], cacc[r]);
            }
        }
        __syncthreads();
    }

    // reduce 4 regs (rows in quad) then across quads (lanes 16, 32 apart)
    float rm = fmaxf(fmaxf(runmax[0], runmax[1]), fmaxf(runmax[2], runmax[3]));
    rm = fmaxf(rm, __shfl_xor(rm, 16));
    rm = fmaxf(rm, __shfl_xor(rm, 32));
    if ((t & 63) < 16) {
        const int n = 16 * w + ln;
        hout[b * 128 + n] = rm + b3[n];
    }
}

// ---------------------------------------------------------------------------
// det motion MLP: 9 -> 32 (relu) -> 64. One block per detection.
// ---------------------------------------------------------------------------
__global__ __launch_bounds__(64) void detmot_kernel(
    const float* __restrict__ det_boxes,
    const float* __restrict__ w1, const float* __restrict__ b1,
    const float* __restrict__ w2, const float* __restrict__ b2,
    float* __restrict__ hout)
{
    __shared__ float sx[9];
    __shared__ float sh[32];
    const int t = threadIdx.x, d = blockIdx.x;
    if (t < 9) sx[t] = det_boxes[d * 9 + t];
    __syncthreads();
    if (t < 32) {
        float a = b1[t];
#pragma unroll
        for (int k = 0; k < 9; ++k) a = fmaf(w1[t * 9 + k], sx[k], a);
        sh[t] = fmaxf(a, 0.f);
    }
    __syncthreads();
    float a = b2[t];
#pragma unroll
    for (int k = 0; k < 32; ++k) a = fmaf(w2[t * 32 + k], sh[k], a);
    hout[d * 128 + 64 + t] = a;
}

// ---------------------------------------------------------------------------
// Fused 2-layer LSTM, row-parallel. One block per track; weights in registers.
// ---------------------------------------------------------------------------
__global__ __launch_bounds__(256, 1) void lstm_kernel(
    const float* __restrict__ track_boxes,
    const float* __restrict__ wih0, const float* __restrict__ whh0,
    const float* __restrict__ bih0, const float* __restrict__ bhh0,
    const float* __restrict__ wih1, const float* __restrict__ whh1,
    const float* __restrict__ bih1, const float* __restrict__ bhh1,
    float* __restrict__ hout)
{
    __shared__ float sx[90];
    __shared__ float sg[256];
    __shared__ __align__(16) float sh0[64];
    __shared__ __align__(16) float sh1[64];

    const int t = threadIdx.x;
    const int m = blockIdx.x;
    const int u = t & 63;

    if (t < 90) sx[t] = track_boxes[m * 90 + t];
    if (t < 64) { sh0[t] = 0.f; sh1[t] = 0.f; }

    float w0[9];
#pragma unroll
    for (int k = 0; k < 9; ++k) w0[k] = wih0[t * 9 + k];
    float4 wr0[16], wi1[16], wr1[16];
    {
        const float4* p0 = (const float4*)(whh0 + t * 64);
        const float4* p1 = (const float4*)(wih1 + t * 64);
        const float4* p2 = (const float4*)(whh1 + t * 64);
#pragma unroll
        for (int k = 0; k < 16; ++k) { wr0[k] = p0[k]; wi1[k] = p1[k]; wr1[k] = p2[k]; }
    }
    const float bias0 = bih0[t] + bhh0[t];
    const float bias1 = bih1[t] + bhh1[t];

    float c0 = 0.f, c1 = 0.f, h1reg = 0.f;
    __syncthreads();

    for (int s = 0; s < 10; ++s) {
        {
            float acc0 = bias0, acc1 = 0.f, acc2 = 0.f, acc3 = 0.f;
#pragma unroll
            for (int k = 0; k < 9; ++k) acc0 = fmaf(w0[k], sx[s * 9 + k], acc0);
            const float4* hv = (const float4*)sh0;
#pragma unroll
            for (int k = 0; k < 16; k += 4) {
                float4 hA = hv[k], hB = hv[k + 1], hC = hv[k + 2], hD = hv[k + 3];
                acc0 = fmaf(wr0[k].x, hA.x, acc0); acc0 = fmaf(wr0[k].y, hA.y, acc0);
                acc0 = fmaf(wr0[k].z, hA.z, acc0); acc0 = fmaf(wr0[k].w, hA.w, acc0);
                acc1 = fmaf(wr0[k+1].x, hB.x, acc1); acc1 = fmaf(wr0[k+1].y, hB.y, acc1);
                acc1 = fmaf(wr0[k+1].z, hB.z, acc1); acc1 = fmaf(wr0[k+1].w, hB.w, acc1);
                acc2 = fmaf(wr0[k+2].x, hC.x, acc2); acc2 = fmaf(wr0[k+2].y, hC.y, acc2);
                acc2 = fmaf(wr0[k+2].z, hC.z, acc2); acc2 = fmaf(wr0[k+2].w, hC.w, acc2);
                acc3 = fmaf(wr0[k+3].x, hD.x, acc3); acc3 = fmaf(wr0[k+3].y, hD.y, acc3);
                acc3 = fmaf(wr0[k+3].z, hD.z, acc3); acc3 = fmaf(wr0[k+3].w, hD.w, acc3);
            }
            sg[t] = (acc0 + acc1) + (acc2 + acc3);
        }
        __syncthreads();
        if (t < 64) {
            const float gi = sg[u], gf = sg[64 + u], gg = sg[128 + u], go = sg[192 + u];
            c0 = sigf(gf) * c0 + sigf(gi) * tanhf(gg);
            sh0[u] = sigf(go) * tanhf(c0);
        }
        __syncthreads();
        {
            float acc0 = bias1, acc1 = 0.f, acc2 = 0.f, acc3 = 0.f;
            const float4* xv = (const float4*)sh0;
            const float4* hv = (const float4*)sh1;
#pragma unroll
            for (int k = 0; k < 16; k += 4) {
                float4 xA = xv[k], xB = xv[k + 1], xC = xv[k + 2], xD = xv[k + 3];
                acc0 = fmaf(wi1[k].x, xA.x, acc0); acc0 = fmaf(wi1[k].y, xA.y, acc0);
                acc0 = fmaf(wi1[k].z, xA.z, acc0); acc0 = fmaf(wi1[k].w, xA.w, acc0);
                acc1 = fmaf(wi1[k+1].x, xB.x, acc1); acc1 = fmaf(wi1[k+1].y, xB.y, acc1);
                acc1 = fmaf(wi1[k+1].z, xB.z, acc1); acc1 = fmaf(wi1[k+1].w, xB.w, acc1);
                acc2 = fmaf(wi1[k+2].x, xC.x, acc2); acc2 = fmaf(wi1[k+2].y, xC.y, acc2);
                acc2 = fmaf(wi1[k+2].z, xC.z, acc2); acc2 = fmaf(wi1[k+2].w, xC.w, acc2);
                acc3 = fmaf(wi1[k+3].x, xD.x, acc3); acc3 = fmaf(wi1[k+3].y, xD.y, acc3);
                acc3 = fmaf(wi1[k+3].z, xD.z, acc3); acc3 = fmaf(wi1[k+3].w, xD.w, acc3);
            }
#pragma unroll
            for (int k = 0; k < 16; k += 4) {
                float4 hA = hv[k], hB = hv[k + 1], hC = hv[k + 2], hD = hv[k + 3];
                acc0 = fmaf(wr1[k].x, hA.x, acc0); acc0 = fmaf(wr1[k].y, hA.y, acc0);
                acc0 = fmaf(wr1[k].z, hA.z, acc0); acc0 = fmaf(wr1[k].w, hA.w, acc0);
                acc1 = fmaf(wr1[k+1].x, hB.x, acc1); acc1 = fmaf(wr1[k+1].y, hB.y, acc1);
                acc1 = fmaf(wr1[k+1].z, hB.z, acc1); acc1 = fmaf(wr1[k+1].w, hB.w, acc1);
                acc2 = fmaf(wr1[k+2].x, hC.x, acc2); acc2 = fmaf(wr1[k+2].y, hC.y, acc2);
                acc2 = fmaf(wr1[k+2].z, hC.z, acc2); acc2 = fmaf(wr1[k+2].w, hC.w, acc2);
                acc3 = fmaf(wr1[k+3].x, hD.x, acc3); acc3 = fmaf(wr1[k+3].y, hD.y, acc3);
                acc3 = fmaf(wr1[k+3].z, hD.z, acc3); acc3 = fmaf(wr1[k+3].w, hD.w, acc3);
            }
            sg[t] = (acc0 + acc1) + (acc2 + acc3);
        }
        __syncthreads();
        if (t < 64) {
            const float gi = sg[u], gf = sg[64 + u], gg = sg[128 + u], go = sg[192 + u];
            c1 = sigf(gf) * c1 + sigf(gi) * tanhf(gg);
            h1reg = sigf(go) * tanhf(c1);
            sh1[u] = h1reg;
        }
        __syncthreads();
    }

    if (t < 64) hout[(size_t)(NDET + m) * 128 + 64 + u] = h1reg;
}

// ---------------------------------------------------------------------------
// EdgeConv GEMMs: Th = h @ wt^T ; Ph = h @ wp^T + bp. One block per vertex.
// ---------------------------------------------------------------------------
__global__ __launch_bounds__(128) void econv_gemm_kernel(
    const float* __restrict__ hin, const float* __restrict__ wt,
    const float* __restrict__ wp, const float* __restrict__ bp,
    float* __restrict__ Th, float* __restrict__ Ph)
{
    __shared__ __align__(16) float srow[128];
    const int t = threadIdx.x, v = blockIdx.x;
    srow[t] = hin[v * 128 + t];
    __syncthreads();
    const float4* hr = (const float4*)srow;
    const float4* wtr = (const float4*)(wt + t * 128);
    const float4* wpr = (const float4*)(wp + t * 128);
    float aT = 0.f, aP = bp[t];
#pragma unroll 8
    for (int k = 0; k < 32; ++k) {
        const float4 h = hr[k];
        const float4 a = wtr[k];
        aT = fmaf(a.x, h.x, aT); aT = fmaf(a.y, h.y, aT);
        aT = fmaf(a.z, h.z, aT); aT = fmaf(a.w, h.w, aT);
        const float4 b = wpr[k];
        aP = fmaf(b.x, h.x, aP); aP = fmaf(b.y, h.y, aP);
        aP = fmaf(b.z, h.z, aP); aP = fmaf(b.w, h.w, aP);
    }
    Th[v * 128 + t] = aT;
    Ph[v * 128 + t] = aP;
}

// ---------------------------------------------------------------------------
// EdgeConv masked neighbor-max + combine + relu. One block per target vertex i.
// ---------------------------------------------------------------------------
__global__ __launch_bounds__(128) void econv_max_kernel(
    const int* __restrict__ adj, const float* __restrict__ Th,
    const float* __restrict__ Ph, const float* __restrict__ bt,
    float* __restrict__ hout)
{
    __shared__ int smask[NV];
    const int t = threadIdx.x, i = blockIdx.x;
    for (int j = t; j < NV; j += 128) smask[j] = (adj[j * NV + i] != 0) || (j == i);
    __syncthreads();
    float m = -1e30f;
    for (int j = 0; j < NV; ++j) {
        if (smask[j]) m = fmaxf(m, Th[j * 128 + t]);
    }
    hout[i * 128 + t] = fmaxf(m - Th[i * 128 + t] + bt[t] + Ph[i * 128 + t], 0.f);
}

// ---------------------------------------------------------------------------
// Affinity stage 1: u = h[:256] @ er_w1^T  ([256,64])
// ---------------------------------------------------------------------------
__global__ __launch_bounds__(64) void uproj_kernel(
    const float* __restrict__ hin, const float* __restrict__ w1,
    float* __restrict__ u)
{
    __shared__ __align__(16) float srow[128];
    const int t = threadIdx.x, i = blockIdx.x;
    srow[t] = hin[i * 128 + t];
    srow[t + 64] = hin[i * 128 + 64 + t];
    __syncthreads();
    const float4* hr = (const float4*)srow;
    const float4* wr = (const float4*)(w1 + t * 128);
    float a = 0.f;
#pragma unroll 8
    for (int k = 0; k < 32; ++k) {
        const float4 h = hr[k], w = wr[k];
        a = fmaf(w.x, h.x, a); a = fmaf(w.y, h.y, a);
        a = fmaf(w.z, h.z, a); a = fmaf(w.w, h.w, a);
    }
    u[i * 64 + t] = a;
}

// ---------------------------------------------------------------------------
// Affinity stage 2: aff[i][j] = sigmoid( sum_k w2[k]*relu(u[j][k]-u[i][k]+b1[k]) + b2 )
// ---------------------------------------------------------------------------
__global__ __launch_bounds__(256) void edge_kernel(
    const float* __restrict__ u, const float* __restrict__ b1,
    const float* __restrict__ w2, const float* __restrict__ b2,
    float* __restrict__ out)
{
    __shared__ float sui[64], sw2[64], sb1[64];
    const int t = threadIdx.x, i = blockIdx.x;
    if (t < 64) { sui[t] = u[i * 64 + t]; sw2[t] = w2[t]; sb1[t] = b1[t]; }
    __syncthreads();
    const float4* ur = (const float4*)(u + t * 64);
    float a = b2[0];
#pragma unroll
    for (int k = 0; k < 16; ++k) {
        const float4 uv = ur[k];
        const int k4 = k * 4;
        a = fmaf(sw2[k4 + 0], fmaxf(uv.x - sui[k4 + 0] + sb1[k4 + 0], 0.f), a);
        a = fmaf(sw2[k4 + 1], fmaxf(uv.y - sui[k4 + 1] + sb1[k4 + 1], 0.f), a);
        a = fmaf(sw2[k4 + 2], fmaxf(uv.z - sui[k4 + 2] + sb1[k4 + 2], 0.f), a);
        a = fmaf(sw2[k4 + 3], fmaxf(uv.w - sui[k4 + 3] + sb1[k4 + 3], 0.f), a);
    }
    out[i * 256 + t] = 1.f / (1.f + expf(-a));
}

// ---------------------------------------------------------------------------
extern "C" void kernel_launch(void* const* d_in, const int* in_sizes, int n_in,
                              void* d_out, int out_size, void* d_ws, size_t ws_size,
                              hipStream_t stream)
{
    const float* det_pts     = (const float*)d_in[0];
    const float* det_boxes   = (const float*)d_in[1];
    const float* track_pts   = (const float*)d_in[2];
    const float* track_boxes = (const float*)d_in[3];
    const int*   adj         = (const int*)d_in[4];
    const float* pn_w1 = (const float*)d_in[5],  *pn_b1 = (const float*)d_in[6];
    const float* pn_w2 = (const float*)d_in[7],  *pn_b2 = (const float*)d_in[8];
    const float* pn_w3 = (const float*)d_in[9],  *pn_b3 = (const float*)d_in[10];
    const float* dm_w1 = (const float*)d_in[11], *dm_b1 = (const float*)d_in[12];
    const float* dm_w2 = (const float*)d_in[13], *dm_b2 = (const float*)d_in[14];
    const float* l0_wih = (const float*)d_in[15], *l0_whh = (const float*)d_in[16];
    const float* l0_bih = (const float*)d_in[17], *l0_bhh = (const float*)d_in[18];
    const float* l1_wih = (const float*)d_in[19], *l1_whh = (const float*)d_in[20];
    const float* l1_bih = (const float*)d_in[21], *l1_bhh = (const float*)d_in[22];
    const float* gc_wt = (const float*)d_in[23], *gc_bt = (const float*)d_in[24];
    const float* gc_wp = (const float*)d_in[25], *gc_bp = (const float*)d_in[26];
    const float* er_w1 = (const float*)d_in[27], *er_b1 = (const float*)d_in[28];
    const float* er_w2 = (const float*)d_in[29], *er_b2 = (const float*)d_in[30];
    float* out = (float*)d_out;

    float* hA = (float*)d_ws;            // [512][128]
    float* hB = hA + NV * 128;           // [512][128]
    float* Th = hB + NV * 128;           // [512][128]
    float* Ph = Th + NV * 128;           // [512][128]
    float* uu = Ph + NV * 128;           // [256][64]

    pointnet_kernel<<<NV, 256, 0, stream>>>(det_pts, track_pts,
        pn_w1, pn_b1, pn_w2, pn_b2, pn_w3, pn_b3, hA);
    detmot_kernel<<<NDET, 64, 0, stream>>>(det_boxes, dm_w1, dm_b1, dm_w2, dm_b2, hA);
    lstm_kernel<<<NTRK, 256, 0, stream>>>(track_boxes,
        l0_wih, l0_whh, l0_bih, l0_bhh, l1_wih, l1_whh, l1_bih, l1_bhh, hA);

    float* hin = hA;
    float* hO  = hB;
    for (int k = 0; k < 4; ++k) {
        econv_gemm_kernel<<<NV, 128, 0, stream>>>(hin,
            gc_wt + (size_t)k * 128 * 128, gc_wp + (size_t)k * 128 * 128,
            gc_bp + (size_t)k * 128, Th, Ph);
        econv_max_kernel<<<NV, 128, 0, stream>>>(adj, Th, Ph,
            gc_bt + (size_t)k * 128, hO);
        float* tmp = hin; hin = hO; hO = tmp;
        if (k == 0) {
            uproj_kernel<<<NDET, 64, 0, stream>>>(hin, er_w1, uu);
            edge_kernel<<<NDET, 256, 0, stream>>>(uu, er_b1, er_w2, er_b2, out);
        }
    }
    uproj_kernel<<<NDET, 64, 0, stream>>>(hin, er_w1, uu);
    edge_kernel<<<NDET, 256, 0, stream>>>(uu, er_b1, er_w2, er_b2, out + NDET * NTRK);
}

// Round 5
// 279.029 us; speedup vs baseline: 2.8314x; 1.5420x over previous
//
#include <hip/hip_runtime.h>
#include <math.h>

#define NDET 256
#define NTRK 256
#define NV   512
#define PPTS 512

typedef short bf16x8 __attribute__((ext_vector_type(8)));
typedef float f32x4  __attribute__((ext_vector_type(4)));

__device__ __forceinline__ float sigf(float x) { return 1.f / (1.f + expf(-x)); }

__device__ __forceinline__ short f2bf(float f) {
    unsigned u = __float_as_uint(f);
    u += 0x7fffu + ((u >> 16) & 1u);          // RNE
    return (short)(u >> 16);
}
__device__ __forceinline__ unsigned pack2bf(float lo, float hi) {
    return (unsigned)(unsigned short)f2bf(lo) | ((unsigned)(unsigned short)f2bf(hi) << 16);
}

// ---------------------------------------------------------------------------
// PointNet with bf16 MFMA for the 64->128 and 128->64 stages.
// ---------------------------------------------------------------------------
__global__ __launch_bounds__(256) void pointnet_kernel(
    const float* __restrict__ det_pts, const float* __restrict__ track_pts,
    const float* __restrict__ w1, const float* __restrict__ b1,
    const float* __restrict__ w2, const float* __restrict__ b2,
    const float* __restrict__ w3, const float* __restrict__ b3,
    float* __restrict__ hout)
{
    __shared__ __align__(16) short sW2[128][72];   // bf16 W2[n][k]
    __shared__ __align__(16) short sW3[64][136];   // bf16 W3[n][k]
    __shared__ __align__(16) short sH1[64][72];    // bf16 h1[pt][k]
    __shared__ __align__(16) short sH2[64][136];   // bf16 h2[pt][k]
    __shared__ __align__(16) float sX[320];        // 64 pts x 5
    __shared__ float sW1f[64][6];
    __shared__ float sB1[64];

    const int t  = threadIdx.x;
    const int b  = blockIdx.x;
    const int w  = t >> 6;          // wave 0..3
    const int ln = t & 15;          // lane&15
    const int kq = (t >> 4) & 3;    // lane>>4 within wave
    const float* x = (b < NDET) ? (det_pts + (size_t)b * PPTS * 5)
                                : (track_pts + (size_t)(b - NDET) * PPTS * 5);

    for (int i = t; i < 8192; i += 256) sW2[i >> 6][i & 63] = f2bf(w2[i]);
    for (int i = t; i < 8192; i += 256) sW3[i >> 7][i & 127] = f2bf(w3[i]);
    for (int i = t; i < 320; i += 256) sW1f[i / 5][i % 5] = w1[i];
    if (t < 64) sB1[t] = b1[t];
    __syncthreads();

    bf16x8 bf2[2][2];
#pragma unroll
    for (int nt = 0; nt < 2; ++nt)
#pragma unroll
        for (int Kt = 0; Kt < 2; ++Kt)
            bf2[nt][Kt] = *(const bf16x8*)&sW2[32 * w + 16 * nt + ln][kq * 8 + 32 * Kt];
    bf16x8 bf3[4];
#pragma unroll
    for (int Kt = 0; Kt < 4; ++Kt)
        bf3[Kt] = *(const bf16x8*)&sW3[16 * w + ln][kq * 8 + 32 * Kt];
    float bn[2];
#pragma unroll
    for (int nt = 0; nt < 2; ++nt) bn[nt] = b2[32 * w + 16 * nt + ln];

    float runmax[4] = {-1e30f, -1e30f, -1e30f, -1e30f};

    const int pt = t & 63;
    for (int c = 0; c < PPTS / 64; ++c) {
        for (int i = t; i < 320; i += 256) sX[i] = x[c * 320 + i];
        __syncthreads();

        // ---- stage 1
        {
            float xv[5];
#pragma unroll
            for (int k = 0; k < 5; ++k) xv[k] = sX[pt * 5 + k];
#pragma unroll
            for (int jj = 0; jj < 8; ++jj) {
                const int d0 = w * 16 + 2 * jj;
                float a0 = sB1[d0], a1 = sB1[d0 + 1];
#pragma unroll
                for (int k = 0; k < 5; ++k) {
                    a0 = fmaf(xv[k], sW1f[d0][k], a0);
                    a1 = fmaf(xv[k], sW1f[d0 + 1][k], a1);
                }
                *(unsigned*)&sH1[pt][d0] = pack2bf(fmaxf(a0, 0.f), fmaxf(a1, 0.f));
            }
        }
        __syncthreads();

        // ---- stage 2 (MFMA)
        {
            bf16x8 af[4][2];
#pragma unroll
            for (int Mt = 0; Mt < 4; ++Mt)
#pragma unroll
                for (int Kt = 0; Kt < 2; ++Kt)
                    af[Mt][Kt] = *(const bf16x8*)&sH1[16 * Mt + ln][kq * 8 + 32 * Kt];
#pragma unroll
            for (int Mt = 0; Mt < 4; ++Mt) {
#pragma unroll
                for (int nt = 0; nt < 2; ++nt) {
                    f32x4 cacc = {0.f, 0.f, 0.f, 0.f};
                    cacc = __builtin_amdgcn_mfma_f32_16x16x32_bf16(af[Mt][0], bf2[nt][0], cacc, 0, 0, 0);
                    cacc = __builtin_amdgcn_mfma_f32_16x16x32_bf16(af[Mt][1], bf2[nt][1], cacc, 0, 0, 0);
                    const int col = 32 * w + 16 * nt + ln;
#pragma unroll
                    for (int r = 0; r < 4; ++r)
                        sH2[16 * Mt + kq * 4 + r][col] = f2bf(fmaxf(cacc[r] + bn[nt], 0.f));
                }
            }
        }
        __syncthreads();

        // ---- stage 3 (MFMA) -> running max
        {
#pragma unroll
            for (int Mt = 0; Mt < 4; ++Mt) {
                f32x4 cacc = {0.f, 0.f, 0.f, 0.f};
#pragma unroll
                for (int Kt = 0; Kt < 4; ++Kt) {
                    const bf16x8 a = *(const bf16x8*)&sH2[16 * Mt + ln][kq * 8 + 32 * Kt];
                    cacc = __builtin_amdgcn_mfma_f32_16x16x32_bf16(a, bf3[Kt], cacc, 0, 0, 0);
                }
#pragma unroll
                for (int r = 0; r < 4; ++r) runmax[r] = fmaxf(runmax[r], cacc[r]);
            }
        }
        __syncthreads();
    }

    float rm = fmaxf(fmaxf(runmax[0], runmax[1]), fmaxf(runmax[2], runmax[3]));
    rm = fmaxf(rm, __shfl_xor(rm, 16));
    rm = fmaxf(rm, __shfl_xor(rm, 32));
    if ((t & 63) < 16) {
        const int n = 16 * w + ln;
        hout[b * 128 + n] = rm + b3[n];
    }
}

// ---------------------------------------------------------------------------
// det motion MLP: 9 -> 32 (relu) -> 64. One block per detection.
// ---------------------------------------------------------------------------
__global__ __launch_bounds__(64) void detmot_kernel(
    const float* __restrict__ det_boxes,
    const float* __restrict__ w1, const float* __restrict__ b1,
    const float* __restrict__ w2, const float* __restrict__ b2,
    float* __restrict__ hout)
{
    __shared__ float sx[9];
    __shared__ float sh[32];
    const int t = threadIdx.x, d = blockIdx.x;
    if (t < 9) sx[t] = det_boxes[d * 9 + t];
    __syncthreads();
    if (t < 32) {
        float a = b1[t];
#pragma unroll
        for (int k = 0; k < 9; ++k) a = fmaf(w1[t * 9 + k], sx[k], a);
        sh[t] = fmaxf(a, 0.f);
    }
    __syncthreads();
    float a = b2[t];
#pragma unroll
    for (int k = 0; k < 32; ++k) a = fmaf(w2[t * 32 + k], sh[k], a);
    hout[d * 128 + 64 + t] = a;
}

// ---------------------------------------------------------------------------
// Fused 2-layer LSTM, row-parallel. One block per track; weights in registers.
// ---------------------------------------------------------------------------
__global__ __launch_bounds__(256, 1) void lstm_kernel(
    const float* __restrict__ track_boxes,
    const float* __restrict__ wih0, const float* __restrict__ whh0,
    const float* __restrict__ bih0, const float* __restrict__ bhh0,
    const float* __restrict__ wih1, const float* __restrict__ whh1,
    const float* __restrict__ bih1, const float* __restrict__ bhh1,
    float* __restrict__ hout)
{
    __shared__ float sx[90];
    __shared__ float sg[256];
    __shared__ __align__(16) float sh0[64];
    __shared__ __align__(16) float sh1[64];

    const int t = threadIdx.x;
    const int m = blockIdx.x;
    const int u = t & 63;

    if (t < 90) sx[t] = track_boxes[m * 90 + t];
    if (t < 64) { sh0[t] = 0.f; sh1[t] = 0.f; }

    float w0[9];
#pragma unroll
    for (int k = 0; k < 9; ++k) w0[k] = wih0[t * 9 + k];
    float4 wr0[16], wi1[16], wr1[16];
    {
        const float4* p0 = (const float4*)(whh0 + t * 64);
        const float4* p1 = (const float4*)(wih1 + t * 64);
        const float4* p2 = (const float4*)(whh1 + t * 64);
#pragma unroll
        for (int k = 0; k < 16; ++k) { wr0[k] = p0[k]; wi1[k] = p1[k]; wr1[k] = p2[k]; }
    }
    const float bias0 = bih0[t] + bhh0[t];
    const float bias1 = bih1[t] + bhh1[t];

    float c0 = 0.f, c1 = 0.f, h1reg = 0.f;
    __syncthreads();

    for (int s = 0; s < 10; ++s) {
        {
            float acc0 = bias0, acc1 = 0.f, acc2 = 0.f, acc3 = 0.f;
#pragma unroll
            for (int k = 0; k < 9; ++k) acc0 = fmaf(w0[k], sx[s * 9 + k], acc0);
            const float4* hv = (const float4*)sh0;
#pragma unroll
            for (int k = 0; k < 16; k += 4) {
                float4 hA = hv[k], hB = hv[k + 1], hC = hv[k + 2], hD = hv[k + 3];
                acc0 = fmaf(wr0[k].x, hA.x, acc0); acc0 = fmaf(wr0[k].y, hA.y, acc0);
                acc0 = fmaf(wr0[k].z, hA.z, acc0); acc0 = fmaf(wr0[k].w, hA.w, acc0);
                acc1 = fmaf(wr0[k+1].x, hB.x, acc1); acc1 = fmaf(wr0[k+1].y, hB.y, acc1);
                acc1 = fmaf(wr0[k+1].z, hB.z, acc1); acc1 = fmaf(wr0[k+1].w, hB.w, acc1);
                acc2 = fmaf(wr0[k+2].x, hC.x, acc2); acc2 = fmaf(wr0[k+2].y, hC.y, acc2);
                acc2 = fmaf(wr0[k+2].z, hC.z, acc2); acc2 = fmaf(wr0[k+2].w, hC.w, acc2);
                acc3 = fmaf(wr0[k+3].x, hD.x, acc3); acc3 = fmaf(wr0[k+3].y, hD.y, acc3);
                acc3 = fmaf(wr0[k+3].z, hD.z, acc3); acc3 = fmaf(wr0[k+3].w, hD.w, acc3);
            }
            sg[t] = (acc0 + acc1) + (acc2 + acc3);
        }
        __syncthreads();
        if (t < 64) {
            const float gi = sg[u], gf = sg[64 + u], gg = sg[128 + u], go = sg[192 + u];
            c0 = sigf(gf) * c0 + sigf(gi) * tanhf(gg);
            sh0[u] = sigf(go) * tanhf(c0);
        }
        __syncthreads();
        {
            float acc0 = bias1, acc1 = 0.f, acc2 = 0.f, acc3 = 0.f;
            const float4* xv = (const float4*)sh0;
            const float4* hv = (const float4*)sh1;
#pragma unroll
            for (int k = 0; k < 16; k += 4) {
                float4 xA = xv[k], xB = xv[k + 1], xC = xv[k + 2], xD = xv[k + 3];
                acc0 = fmaf(wi1[k].x, xA.x, acc0); acc0 = fmaf(wi1[k].y, xA.y, acc0);
                acc0 = fmaf(wi1[k].z, xA.z, acc0); acc0 = fmaf(wi1[k].w, xA.w, acc0);
                acc1 = fmaf(wi1[k+1].x, xB.x, acc1); acc1 = fmaf(wi1[k+1].y, xB.y, acc1);
                acc1 = fmaf(wi1[k+1].z, xB.z, acc1); acc1 = fmaf(wi1[k+1].w, xB.w, acc1);
                acc2 = fmaf(wi1[k+2].x, xC.x, acc2); acc2 = fmaf(wi1[k+2].y, xC.y, acc2);
                acc2 = fmaf(wi1[k+2].z, xC.z, acc2); acc2 = fmaf(wi1[k+2].w, xC.w, acc2);
                acc3 = fmaf(wi1[k+3].x, xD.x, acc3); acc3 = fmaf(wi1[k+3].y, xD.y, acc3);
                acc3 = fmaf(wi1[k+3].z, xD.z, acc3); acc3 = fmaf(wi1[k+3].w, xD.w, acc3);
            }
#pragma unroll
            for (int k = 0; k < 16; k += 4) {
                float4 hA = hv[k], hB = hv[k + 1], hC = hv[k + 2], hD = hv[k + 3];
                acc0 = fmaf(wr1[k].x, hA.x, acc0); acc0 = fmaf(wr1[k].y, hA.y, acc0);
                acc0 = fmaf(wr1[k].z, hA.z, acc0); acc0 = fmaf(wr1[k].w, hA.w, acc0);
                acc1 = fmaf(wr1[k+1].x, hB.x, acc1); acc1 = fmaf(wr1[k+1].y, hB.y, acc1);
                acc1 = fmaf(wr1[k+1].z, hB.z, acc1); acc1 = fmaf(wr1[k+1].w, hB.w, acc1);
                acc2 = fmaf(wr1[k+2].x, hC.x, acc2); acc2 = fmaf(wr1[k+2].y, hC.y, acc2);
                acc2 = fmaf(wr1[k+2].z, hC.z, acc2); acc2 = fmaf(wr1[k+2].w, hC.w, acc2);
                acc3 = fmaf(wr1[k+3].x, hD.x, acc3); acc3 = fmaf(wr1[k+3].y, hD.y, acc3);
                acc3 = fmaf(wr1[k+3].z, hD.z, acc3); acc3 = fmaf(wr1[k+3].w, hD.w, acc3);
            }
            sg[t] = (acc0 + acc1) + (acc2 + acc3);
        }
        __syncthreads();
        if (t < 64) {
            const float gi = sg[u], gf = sg[64 + u], gg = sg[128 + u], go = sg[192 + u];
            c1 = sigf(gf) * c1 + sigf(gi) * tanhf(gg);
            h1reg = sigf(go) * tanhf(c1);
            sh1[u] = h1reg;
        }
        __syncthreads();
    }

    if (t < 64) hout[(size_t)(NDET + m) * 128 + 64 + u] = h1reg;
}

// ---------------------------------------------------------------------------
// EdgeConv GEMMs: Th = h @ wt^T ; Ph = h @ wp^T + bp. One block per vertex.
// ---------------------------------------------------------------------------
__global__ __launch_bounds__(128) void econv_gemm_kernel(
    const float* __restrict__ hin, const float* __restrict__ wt,
    const float* __restrict__ wp, const float* __restrict__ bp,
    float* __restrict__ Th, float* __restrict__ Ph)
{
    __shared__ __align__(16) float srow[128];
    const int t = threadIdx.x, v = blockIdx.x;
    srow[t] = hin[v * 128 + t];
    __syncthreads();
    const float4* hr = (const float4*)srow;
    const float4* wtr = (const float4*)(wt + t * 128);
    const float4* wpr = (const float4*)(wp + t * 128);
    float aT = 0.f, aP = bp[t];
#pragma unroll 8
    for (int k = 0; k < 32; ++k) {
        const float4 h = hr[k];
        const float4 a = wtr[k];
        aT = fmaf(a.x, h.x, aT); aT = fmaf(a.y, h.y, aT);
        aT = fmaf(a.z, h.z, aT); aT = fmaf(a.w, h.w, aT);
        const float4 b = wpr[k];
        aP = fmaf(b.x, h.x, aP); aP = fmaf(b.y, h.y, aP);
        aP = fmaf(b.z, h.z, aP); aP = fmaf(b.w, h.w, aP);
    }
    Th[v * 128 + t] = aT;
    Ph[v * 128 + t] = aP;
}

// ---------------------------------------------------------------------------
// EdgeConv masked neighbor-max + combine + relu. One block per target vertex i.
// Branch-free: mask as additive bias (0 / -3e38), 16 unconditional loads in
// flight per trip. Self-loop guarantees a real max, so the bias trick is exact.
// ---------------------------------------------------------------------------
__global__ __launch_bounds__(128) void econv_max_kernel(
    const int* __restrict__ adj, const float* __restrict__ Th,
    const float* __restrict__ Ph, const float* __restrict__ bt,
    float* __restrict__ hout)
{
    __shared__ float sneg[NV];     // 0 if j is a source-neighbor of i, else -3e38
    const int t = threadIdx.x, i = blockIdx.x;
    for (int j = t; j < NV; j += 128)
        sneg[j] = ((adj[j * NV + i] != 0) || (j == i)) ? 0.f : -3e38f;
    __syncthreads();

    const float* __restrict__ thp = Th + t;
    float m = -3e38f;
#pragma unroll 1
    for (int j0 = 0; j0 < NV; j0 += 16) {
        float v[16];
#pragma unroll
        for (int jj = 0; jj < 16; ++jj) v[jj] = thp[(j0 + jj) * 128];
#pragma unroll
        for (int jj = 0; jj < 16; ++jj) m = fmaxf(m, v[jj] + sneg[j0 + jj]);
    }
    hout[i * 128 + t] = fmaxf(m - Th[i * 128 + t] + bt[t] + Ph[i * 128 + t], 0.f);
}

// ---------------------------------------------------------------------------
// Affinity stage 1: u = h[:256] @ er_w1^T  ([256,64])
// ---------------------------------------------------------------------------
__global__ __launch_bounds__(64) void uproj_kernel(
    const float* __restrict__ hin, const float* __restrict__ w1,
    float* __restrict__ u)
{
    __shared__ __align__(16) float srow[128];
    const int t = threadIdx.x, i = blockIdx.x;
    srow[t] = hin[i * 128 + t];
    srow[t + 64] = hin[i * 128 + 64 + t];
    __syncthreads();
    const float4* hr = (const float4*)srow;
    const float4* wr = (const float4*)(w1 + t * 128);
    float a = 0.f;
#pragma unroll 8
    for (int k = 0; k < 32; ++k) {
        const float4 h = hr[k], w = wr[k];
        a = fmaf(w.x, h.x, a); a = fmaf(w.y, h.y, a);
        a = fmaf(w.z, h.z, a); a = fmaf(w.w, h.w, a);
    }
    u[i * 64 + t] = a;
}

// ---------------------------------------------------------------------------
// Affinity stage 2: aff[i][j] = sigmoid( sum_k w2[k]*relu(u[j][k]-u[i][k]+b1[k]) + b2 )
// ---------------------------------------------------------------------------
__global__ __launch_bounds__(256) void edge_kernel(
    const float* __restrict__ u, const float* __restrict__ b1,
    const float* __restrict__ w2, const float* __restrict__ b2,
    float* __restrict__ out)
{
    __shared__ float sui[64], sw2[64], sb1[64];
    const int t = threadIdx.x, i = blockIdx.x;
    if (t < 64) { sui[t] = u[i * 64 + t]; sw2[t] = w2[t]; sb1[t] = b1[t]; }
    __syncthreads();
    const float4* ur = (const float4*)(u + t * 64);
    float a = b2[0];
#pragma unroll
    for (int k = 0; k < 16; ++k) {
        const float4 uv = ur[k];
        const int k4 = k * 4;
        a = fmaf(sw2[k4 + 0], fmaxf(uv.x - sui[k4 + 0] + sb1[k4 + 0], 0.f), a);
        a = fmaf(sw2[k4 + 1], fmaxf(uv.y - sui[k4 + 1] + sb1[k4 + 1], 0.f), a);
        a = fmaf(sw2[k4 + 2], fmaxf(uv.z - sui[k4 + 2] + sb1[k4 + 2], 0.f), a);
        a = fmaf(sw2[k4 + 3], fmaxf(uv.w - sui[k4 + 3] + sb1[k4 + 3], 0.f), a);
    }
    out[i * 256 + t] = 1.f / (1.f + expf(-a));
}

// ---------------------------------------------------------------------------
extern "C" void kernel_launch(void* const* d_in, const int* in_sizes, int n_in,
                              void* d_out, int out_size, void* d_ws, size_t ws_size,
                              hipStream_t stream)
{
    const float* det_pts     = (const float*)d_in[0];
    const float* det_boxes   = (const float*)d_in[1];
    const float* track_pts   = (const float*)d_in[2];
    const float* track_boxes = (const float*)d_in[3];
    const int*   adj         = (const int*)d_in[4];
    const float* pn_w1 = (const float*)d_in[5],  *pn_b1 = (const float*)d_in[6];
    const float* pn_w2 = (const float*)d_in[7],  *pn_b2 = (const float*)d_in[8];
    const float* pn_w3 = (const float*)d_in[9],  *pn_b3 = (const float*)d_in[10];
    const float* dm_w1 = (const float*)d_in[11], *dm_b1 = (const float*)d_in[12];
    const float* dm_w2 = (const float*)d_in[13], *dm_b2 = (const float*)d_in[14];
    const float* l0_wih = (const float*)d_in[15], *l0_whh = (const float*)d_in[16];
    const float* l0_bih = (const float*)d_in[17], *l0_bhh = (const float*)d_in[18];
    const float* l1_wih = (const float*)d_in[19], *l1_whh = (const float*)d_in[20];
    const float* l1_bih = (const float*)d_in[21], *l1_bhh = (const float*)d_in[22];
    const float* gc_wt = (const float*)d_in[23], *gc_bt = (const float*)d_in[24];
    const float* gc_wp = (const float*)d_in[25], *gc_bp = (const float*)d_in[26];
    const float* er_w1 = (const float*)d_in[27], *er_b1 = (const float*)d_in[28];
    const float* er_w2 = (const float*)d_in[29], *er_b2 = (const float*)d_in[30];
    float* out = (float*)d_out;

    float* hA = (float*)d_ws;            // [512][128]
    float* hB = hA + NV * 128;           // [512][128]
    float* Th = hB + NV * 128;           // [512][128]
    float* Ph = Th + NV * 128;           // [512][128]
    float* uu = Ph + NV * 128;           // [256][64]

    pointnet_kernel<<<NV, 256, 0, stream>>>(det_pts, track_pts,
        pn_w1, pn_b1, pn_w2, pn_b2, pn_w3, pn_b3, hA);
    detmot_kernel<<<NDET, 64, 0, stream>>>(det_boxes, dm_w1, dm_b1, dm_w2, dm_b2, hA);
    lstm_kernel<<<NTRK, 256, 0, stream>>>(track_boxes,
        l0_wih, l0_whh, l0_bih, l0_bhh, l1_wih, l1_whh, l1_bih, l1_bhh, hA);

    float* hin = hA;
    float* hO  = hB;
    for (int k = 0; k < 4; ++k) {
        econv_gemm_kernel<<<NV, 128, 0, stream>>>(hin,
            gc_wt + (size_t)k * 128 * 128, gc_wp + (size_t)k * 128 * 128,
            gc_bp + (size_t)k * 128, Th, Ph);
        econv_max_kernel<<<NV, 128, 0, stream>>>(adj, Th, Ph,
            gc_bt + (size_t)k * 128, hO);
        float* tmp = hin; hin = hO; hO = tmp;
        if (k == 0) {
            uproj_kernel<<<NDET, 64, 0, stream>>>(hin, er_w1, uu);
            edge_kernel<<<NDET, 256, 0, stream>>>(uu, er_b1, er_w2, er_b2, out);
        }
    }
    uproj_kernel<<<NDET, 64, 0, stream>>>(hin, er_w1, uu);
    edge_kernel<<<NDET, 256, 0, stream>>>(uu, er_b1, er_w2, er_b2, out + NDET * NTRK);
}

// Round 6
// 246.355 us; speedup vs baseline: 3.2069x; 1.1326x over previous
//
#include <hip/hip_runtime.h>
#include <math.h>

#define NDET 256
#define NTRK 256
#define NV   512
#define PPTS 512

typedef short bf16x8 __attribute__((ext_vector_type(8)));
typedef float f32x4  __attribute__((ext_vector_type(4)));

__device__ __forceinline__ float sigf(float x) { return 1.f / (1.f + expf(-x)); }

__device__ __forceinline__ short f2bf(float f) {
    unsigned u = __float_as_uint(f);
    u += 0x7fffu + ((u >> 16) & 1u);          // RNE
    return (short)(u >> 16);
}
__device__ __forceinline__ unsigned pack2bf(float lo, float hi) {
    return (unsigned)(unsigned short)f2bf(lo) | ((unsigned)(unsigned short)f2bf(hi) << 16);
}

// ---------------------------------------------------------------------------
// PointNet (bf16 MFMA stages 2/3) + fused det-motion MLP tail for det blocks.
// ---------------------------------------------------------------------------
__global__ __launch_bounds__(256) void pointnet_kernel(
    const float* __restrict__ det_pts, const float* __restrict__ track_pts,
    const float* __restrict__ w1, const float* __restrict__ b1,
    const float* __restrict__ w2, const float* __restrict__ b2,
    const float* __restrict__ w3, const float* __restrict__ b3,
    const float* __restrict__ det_boxes,
    const float* __restrict__ dw1, const float* __restrict__ db1,
    const float* __restrict__ dw2, const float* __restrict__ db2,
    float* __restrict__ hout)
{
    __shared__ __align__(16) short sW2[128][72];   // bf16 W2[n][k]
    __shared__ __align__(16) short sW3[64][136];   // bf16 W3[n][k]
    __shared__ __align__(16) short sH1[64][72];    // bf16 h1[pt][k]
    __shared__ __align__(16) short sH2[64][136];   // bf16 h2[pt][k]
    __shared__ __align__(16) float sX[320];        // 64 pts x 5
    __shared__ float sW1f[64][6];
    __shared__ float sB1[64];
    __shared__ float sbox[9];
    __shared__ float sh32[32];

    const int t  = threadIdx.x;
    const int b  = blockIdx.x;
    const int w  = t >> 6;          // wave 0..3
    const int ln = t & 15;          // lane&15
    const int kq = (t >> 4) & 3;    // lane>>4 within wave
    const float* x = (b < NDET) ? (det_pts + (size_t)b * PPTS * 5)
                                : (track_pts + (size_t)(b - NDET) * PPTS * 5);

    for (int i = t; i < 8192; i += 256) sW2[i >> 6][i & 63] = f2bf(w2[i]);
    for (int i = t; i < 8192; i += 256) sW3[i >> 7][i & 127] = f2bf(w3[i]);
    for (int i = t; i < 320; i += 256) sW1f[i / 5][i % 5] = w1[i];
    if (t < 64) sB1[t] = b1[t];
    __syncthreads();

    bf16x8 bf2[2][2];
#pragma unroll
    for (int nt = 0; nt < 2; ++nt)
#pragma unroll
        for (int Kt = 0; Kt < 2; ++Kt)
            bf2[nt][Kt] = *(const bf16x8*)&sW2[32 * w + 16 * nt + ln][kq * 8 + 32 * Kt];
    bf16x8 bf3[4];
#pragma unroll
    for (int Kt = 0; Kt < 4; ++Kt)
        bf3[Kt] = *(const bf16x8*)&sW3[16 * w + ln][kq * 8 + 32 * Kt];
    float bn[2];
#pragma unroll
    for (int nt = 0; nt < 2; ++nt) bn[nt] = b2[32 * w + 16 * nt + ln];

    float runmax[4] = {-1e30f, -1e30f, -1e30f, -1e30f};

    const int pt = t & 63;
    for (int c = 0; c < PPTS / 64; ++c) {
        for (int i = t; i < 320; i += 256) sX[i] = x[c * 320 + i];
        __syncthreads();

        // ---- stage 1
        {
            float xv[5];
#pragma unroll
            for (int k = 0; k < 5; ++k) xv[k] = sX[pt * 5 + k];
#pragma unroll
            for (int jj = 0; jj < 8; ++jj) {
                const int d0 = w * 16 + 2 * jj;
                float a0 = sB1[d0], a1 = sB1[d0 + 1];
#pragma unroll
                for (int k = 0; k < 5; ++k) {
                    a0 = fmaf(xv[k], sW1f[d0][k], a0);
                    a1 = fmaf(xv[k], sW1f[d0 + 1][k], a1);
                }
                *(unsigned*)&sH1[pt][d0] = pack2bf(fmaxf(a0, 0.f), fmaxf(a1, 0.f));
            }
        }
        __syncthreads();

        // ---- stage 2 (MFMA)
        {
            bf16x8 af[4][2];
#pragma unroll
            for (int Mt = 0; Mt < 4; ++Mt)
#pragma unroll
                for (int Kt = 0; Kt < 2; ++Kt)
                    af[Mt][Kt] = *(const bf16x8*)&sH1[16 * Mt + ln][kq * 8 + 32 * Kt];
#pragma unroll
            for (int Mt = 0; Mt < 4; ++Mt) {
#pragma unroll
                for (int nt = 0; nt < 2; ++nt) {
                    f32x4 cacc = {0.f, 0.f, 0.f, 0.f};
                    cacc = __builtin_amdgcn_mfma_f32_16x16x32_bf16(af[Mt][0], bf2[nt][0], cacc, 0, 0, 0);
                    cacc = __builtin_amdgcn_mfma_f32_16x16x32_bf16(af[Mt][1], bf2[nt][1], cacc, 0, 0, 0);
                    const int col = 32 * w + 16 * nt + ln;
#pragma unroll
                    for (int r = 0; r < 4; ++r)
                        sH2[16 * Mt + kq * 4 + r][col] = f2bf(fmaxf(cacc[r] + bn[nt], 0.f));
                }
            }
        }
        __syncthreads();

        // ---- stage 3 (MFMA) -> running max
        {
#pragma unroll
            for (int Mt = 0; Mt < 4; ++Mt) {
                f32x4 cacc = {0.f, 0.f, 0.f, 0.f};
#pragma unroll
                for (int Kt = 0; Kt < 4; ++Kt) {
                    const bf16x8 a = *(const bf16x8*)&sH2[16 * Mt + ln][kq * 8 + 32 * Kt];
                    cacc = __builtin_amdgcn_mfma_f32_16x16x32_bf16(a, bf3[Kt], cacc, 0, 0, 0);
                }
#pragma unroll
                for (int r = 0; r < 4; ++r) runmax[r] = fmaxf(runmax[r], cacc[r]);
            }
        }
        __syncthreads();
    }

    float rm = fmaxf(fmaxf(runmax[0], runmax[1]), fmaxf(runmax[2], runmax[3]));
    rm = fmaxf(rm, __shfl_xor(rm, 16));
    rm = fmaxf(rm, __shfl_xor(rm, 32));
    if ((t & 63) < 16) {
        const int n = 16 * w + ln;
        hout[b * 128 + n] = rm + b3[n];
    }

    // ---- fused det-motion MLP (det blocks only): 9 -> 32 relu -> 64
    if (b < NDET) {
        if (t < 9) sbox[t] = det_boxes[b * 9 + t];
        __syncthreads();
        if (t < 32) {
            float a = db1[t];
#pragma unroll
            for (int k = 0; k < 9; ++k) a = fmaf(dw1[t * 9 + k], sbox[k], a);
            sh32[t] = fmaxf(a, 0.f);
        }
        __syncthreads();
        if (t < 64) {
            float a = db2[t];
#pragma unroll
            for (int k = 0; k < 32; ++k) a = fmaf(dw2[t * 32 + k], sh32[k], a);
            hout[b * 128 + 64 + t] = a;
        }
    }
}

// ---------------------------------------------------------------------------
// Fused 2-layer LSTM, row-parallel. One block per track; weights in registers.
// ---------------------------------------------------------------------------
__global__ __launch_bounds__(256, 1) void lstm_kernel(
    const float* __restrict__ track_boxes,
    const float* __restrict__ wih0, const float* __restrict__ whh0,
    const float* __restrict__ bih0, const float* __restrict__ bhh0,
    const float* __restrict__ wih1, const float* __restrict__ whh1,
    const float* __restrict__ bih1, const float* __restrict__ bhh1,
    float* __restrict__ hout)
{
    __shared__ float sx[90];
    __shared__ float sg[256];
    __shared__ __align__(16) float sh0[64];
    __shared__ __align__(16) float sh1[64];

    const int t = threadIdx.x;
    const int m = blockIdx.x;
    const int u = t & 63;

    if (t < 90) sx[t] = track_boxes[m * 90 + t];
    if (t < 64) { sh0[t] = 0.f; sh1[t] = 0.f; }

    float w0[9];
#pragma unroll
    for (int k = 0; k < 9; ++k) w0[k] = wih0[t * 9 + k];
    float4 wr0[16], wi1[16], wr1[16];
    {
        const float4* p0 = (const float4*)(whh0 + t * 64);
        const float4* p1 = (const float4*)(wih1 + t * 64);
        const float4* p2 = (const float4*)(whh1 + t * 64);
#pragma unroll
        for (int k = 0; k < 16; ++k) { wr0[k] = p0[k]; wi1[k] = p1[k]; wr1[k] = p2[k]; }
    }
    const float bias0 = bih0[t] + bhh0[t];
    const float bias1 = bih1[t] + bhh1[t];

    float c0 = 0.f, c1 = 0.f, h1reg = 0.f;
    __syncthreads();

    for (int s = 0; s < 10; ++s) {
        {
            float acc0 = bias0, acc1 = 0.f, acc2 = 0.f, acc3 = 0.f;
#pragma unroll
            for (int k = 0; k < 9; ++k) acc0 = fmaf(w0[k], sx[s * 9 + k], acc0);
            const float4* hv = (const float4*)sh0;
#pragma unroll
            for (int k = 0; k < 16; k += 4) {
                float4 hA = hv[k], hB = hv[k + 1], hC = hv[k + 2], hD = hv[k + 3];
                acc0 = fmaf(wr0[k].x, hA.x, acc0); acc0 = fmaf(wr0[k].y, hA.y, acc0);
                acc0 = fmaf(wr0[k].z, hA.z, acc0); acc0 = fmaf(wr0[k].w, hA.w, acc0);
                acc1 = fmaf(wr0[k+1].x, hB.x, acc1); acc1 = fmaf(wr0[k+1].y, hB.y, acc1);
                acc1 = fmaf(wr0[k+1].z, hB.z, acc1); acc1 = fmaf(wr0[k+1].w, hB.w, acc1);
                acc2 = fmaf(wr0[k+2].x, hC.x, acc2); acc2 = fmaf(wr0[k+2].y, hC.y, acc2);
                acc2 = fmaf(wr0[k+2].z, hC.z, acc2); acc2 = fmaf(wr0[k+2].w, hC.w, acc2);
                acc3 = fmaf(wr0[k+3].x, hD.x, acc3); acc3 = fmaf(wr0[k+3].y, hD.y, acc3);
                acc3 = fmaf(wr0[k+3].z, hD.z, acc3); acc3 = fmaf(wr0[k+3].w, hD.w, acc3);
            }
            sg[t] = (acc0 + acc1) + (acc2 + acc3);
        }
        __syncthreads();
        if (t < 64) {
            const float gi = sg[u], gf = sg[64 + u], gg = sg[128 + u], go = sg[192 + u];
            c0 = sigf(gf) * c0 + sigf(gi) * tanhf(gg);
            sh0[u] = sigf(go) * tanhf(c0);
        }
        __syncthreads();
        {
            float acc0 = bias1, acc1 = 0.f, acc2 = 0.f, acc3 = 0.f;
            const float4* xv = (const float4*)sh0;
            const float4* hv = (const float4*)sh1;
#pragma unroll
            for (int k = 0; k < 16; k += 4) {
                float4 xA = xv[k], xB = xv[k + 1], xC = xv[k + 2], xD = xv[k + 3];
                acc0 = fmaf(wi1[k].x, xA.x, acc0); acc0 = fmaf(wi1[k].y, xA.y, acc0);
                acc0 = fmaf(wi1[k].z, xA.z, acc0); acc0 = fmaf(wi1[k].w, xA.w, acc0);
                acc1 = fmaf(wi1[k+1].x, xB.x, acc1); acc1 = fmaf(wi1[k+1].y, xB.y, acc1);
                acc1 = fmaf(wi1[k+1].z, xB.z, acc1); acc1 = fmaf(wi1[k+1].w, xB.w, acc1);
                acc2 = fmaf(wi1[k+2].x, xC.x, acc2); acc2 = fmaf(wi1[k+2].y, xC.y, acc2);
                acc2 = fmaf(wi1[k+2].z, xC.z, acc2); acc2 = fmaf(wi1[k+2].w, xC.w, acc2);
                acc3 = fmaf(wi1[k+3].x, xD.x, acc3); acc3 = fmaf(wi1[k+3].y, xD.y, acc3);
                acc3 = fmaf(wi1[k+3].z, xD.z, acc3); acc3 = fmaf(wi1[k+3].w, xD.w, acc3);
            }
#pragma unroll
            for (int k = 0; k < 16; k += 4) {
                float4 hA = hv[k], hB = hv[k + 1], hC = hv[k + 2], hD = hv[k + 3];
                acc0 = fmaf(wr1[k].x, hA.x, acc0); acc0 = fmaf(wr1[k].y, hA.y, acc0);
                acc0 = fmaf(wr1[k].z, hA.z, acc0); acc0 = fmaf(wr1[k].w, hA.w, acc0);
                acc1 = fmaf(wr1[k+1].x, hB.x, acc1); acc1 = fmaf(wr1[k+1].y, hB.y, acc1);
                acc1 = fmaf(wr1[k+1].z, hB.z, acc1); acc1 = fmaf(wr1[k+1].w, hB.w, acc1);
                acc2 = fmaf(wr1[k+2].x, hC.x, acc2); acc2 = fmaf(wr1[k+2].y, hC.y, acc2);
                acc2 = fmaf(wr1[k+2].z, hC.z, acc2); acc2 = fmaf(wr1[k+2].w, hC.w, acc2);
                acc3 = fmaf(wr1[k+3].x, hD.x, acc3); acc3 = fmaf(wr1[k+3].y, hD.y, acc3);
                acc3 = fmaf(wr1[k+3].z, hD.z, acc3); acc3 = fmaf(wr1[k+3].w, hD.w, acc3);
            }
            sg[t] = (acc0 + acc1) + (acc2 + acc3);
        }
        __syncthreads();
        if (t < 64) {
            const float gi = sg[u], gf = sg[64 + u], gg = sg[128 + u], go = sg[192 + u];
            c1 = sigf(gf) * c1 + sigf(gi) * tanhf(gg);
            h1reg = sigf(go) * tanhf(c1);
            sh1[u] = h1reg;
        }
        __syncthreads();
    }

    if (t < 64) hout[(size_t)(NDET + m) * 128 + 64 + u] = h1reg;
}

// ---------------------------------------------------------------------------
// EdgeConv layer-0 GEMMs: Th = h @ wt^T ; Ph = h @ wp^T + bp. Block per vertex.
// ---------------------------------------------------------------------------
__global__ __launch_bounds__(128) void econv_gemm_kernel(
    const float* __restrict__ hin, const float* __restrict__ wt,
    const float* __restrict__ wp, const float* __restrict__ bp,
    float* __restrict__ Th, float* __restrict__ Ph)
{
    __shared__ __align__(16) float srow[128];
    const int t = threadIdx.x, v = blockIdx.x;
    srow[t] = hin[v * 128 + t];
    __syncthreads();
    const float4* hr = (const float4*)srow;
    const float4* wtr = (const float4*)(wt + t * 128);
    const float4* wpr = (const float4*)(wp + t * 128);
    float aT = 0.f, aP = bp[t];
#pragma unroll 8
    for (int k = 0; k < 32; ++k) {
        const float4 h = hr[k];
        const float4 a = wtr[k];
        aT = fmaf(a.x, h.x, aT); aT = fmaf(a.y, h.y, aT);
        aT = fmaf(a.z, h.z, aT); aT = fmaf(a.w, h.w, aT);
        const float4 b = wpr[k];
        aP = fmaf(b.x, h.x, aP); aP = fmaf(b.y, h.y, aP);
        aP = fmaf(b.z, h.z, aP); aP = fmaf(b.w, h.w, aP);
    }
    Th[v * 128 + t] = aT;
    Ph[v * 128 + t] = aP;
}

// ---------------------------------------------------------------------------
// Fused EdgeConv: masked neighbor-max + combine + relu (h_i stays in LDS),
// then OPTIONAL next-layer GEMM (Thn/Phn) and OPTIONAL uproj (u row, i<256).
// Neighbor-max is vectorized: j split mod-4 across thread-groups, float4 rows.
// Mask as additive bias (0/-3e38) — exact, self-loop guarantees a real max.
// ---------------------------------------------------------------------------
__global__ __launch_bounds__(128) void econv_fused_kernel(
    const int* __restrict__ adj, const float* __restrict__ Th,
    const float* __restrict__ Ph, const float* __restrict__ bt,
    const float* __restrict__ wtn, const float* __restrict__ wpn,
    const float* __restrict__ bpn,
    const float* __restrict__ erw1, float* __restrict__ uu,
    float* __restrict__ Thn, float* __restrict__ Phn)
{
    __shared__ float sneg[NV];                       // 0 / -3e38 mask bias
    __shared__ __align__(16) float4 sred[4][32];     // per-group partial max
    __shared__ __align__(16) float sh[128];          // h_i row

    const int t = threadIdx.x, i = blockIdx.x;
    const int l32 = t & 31, grp = t >> 5;

    for (int j = t; j < NV; j += 128)
        sneg[j] = ((adj[j * NV + i] != 0) || (j == i)) ? 0.f : -3e38f;

    // prefetch own-row terms (overlaps with mask build + j-loop)
    const float thi = Th[i * 128 + t];
    const float phi = Ph[i * 128 + t];
    const float btv = bt[t];
    __syncthreads();

    float4 mx = {-3e38f, -3e38f, -3e38f, -3e38f};
    const float* __restrict__ thp = Th + 4 * l32;
#pragma unroll 4
    for (int jb = 0; jb < NV; jb += 16) {
        float4 v[4];
#pragma unroll
        for (int jj = 0; jj < 4; ++jj)
            v[jj] = *(const float4*)&thp[(size_t)(jb + 4 * jj + grp) * 128];
#pragma unroll
        for (int jj = 0; jj < 4; ++jj) {
            const float s = sneg[jb + 4 * jj + grp];
            mx.x = fmaxf(mx.x, v[jj].x + s);
            mx.y = fmaxf(mx.y, v[jj].y + s);
            mx.z = fmaxf(mx.z, v[jj].z + s);
            mx.w = fmaxf(mx.w, v[jj].w + s);
        }
    }
    sred[grp][l32] = mx;
    __syncthreads();

    const float* rf = (const float*)sred;
    const float m = fmaxf(fmaxf(rf[t], rf[128 + t]), fmaxf(rf[256 + t], rf[384 + t]));
    sh[t] = fmaxf(m - thi + btv + phi, 0.f);
    __syncthreads();

    const float4* hr = (const float4*)sh;
    if (wtn) {
        const float4* wtr = (const float4*)(wtn + t * 128);
        const float4* wpr = (const float4*)(wpn + t * 128);
        float aT = 0.f, aP = bpn[t];
#pragma unroll 8
        for (int k = 0; k < 32; ++k) {
            const float4 h = hr[k];
            const float4 a = wtr[k];
            aT = fmaf(a.x, h.x, aT); aT = fmaf(a.y, h.y, aT);
            aT = fmaf(a.z, h.z, aT); aT = fmaf(a.w, h.w, aT);
            const float4 b = wpr[k];
            aP = fmaf(b.x, h.x, aP); aP = fmaf(b.y, h.y, aP);
            aP = fmaf(b.z, h.z, aP); aP = fmaf(b.w, h.w, aP);
        }
        Thn[i * 128 + t] = aT;
        Phn[i * 128 + t] = aP;
    }
    if (erw1 && i < NDET && t < 64) {
        const float4* wr = (const float4*)(erw1 + t * 128);
        float a = 0.f;
#pragma unroll 8
        for (int k = 0; k < 32; ++k) {
            const float4 h = hr[k], wv = wr[k];
            a = fmaf(wv.x, h.x, a); a = fmaf(wv.y, h.y, a);
            a = fmaf(wv.z, h.z, a); a = fmaf(wv.w, h.w, a);
        }
        uu[i * 64 + t] = a;
    }
}

// ---------------------------------------------------------------------------
// Affinity: aff[i][j] = sigmoid( sum_k w2[k]*relu(u[j][k]-u[i][k]+b1[k]) + b2 )
// ---------------------------------------------------------------------------
__global__ __launch_bounds__(256) void edge_kernel(
    const float* __restrict__ u, const float* __restrict__ b1,
    const float* __restrict__ w2, const float* __restrict__ b2,
    float* __restrict__ out)
{
    __shared__ float sui[64], sw2[64], sb1[64];
    const int t = threadIdx.x, i = blockIdx.x;
    if (t < 64) { sui[t] = u[i * 64 + t]; sw2[t] = w2[t]; sb1[t] = b1[t]; }
    __syncthreads();
    const float4* ur = (const float4*)(u + t * 64);
    float a = b2[0];
#pragma unroll
    for (int k = 0; k < 16; ++k) {
        const float4 uv = ur[k];
        const int k4 = k * 4;
        a = fmaf(sw2[k4 + 0], fmaxf(uv.x - sui[k4 + 0] + sb1[k4 + 0], 0.f), a);
        a = fmaf(sw2[k4 + 1], fmaxf(uv.y - sui[k4 + 1] + sb1[k4 + 1], 0.f), a);
        a = fmaf(sw2[k4 + 2], fmaxf(uv.z - sui[k4 + 2] + sb1[k4 + 2], 0.f), a);
        a = fmaf(sw2[k4 + 3], fmaxf(uv.w - sui[k4 + 3] + sb1[k4 + 3], 0.f), a);
    }
    out[i * 256 + t] = 1.f / (1.f + expf(-a));
}

// ---------------------------------------------------------------------------
extern "C" void kernel_launch(void* const* d_in, const int* in_sizes, int n_in,
                              void* d_out, int out_size, void* d_ws, size_t ws_size,
                              hipStream_t stream)
{
    const float* det_pts     = (const float*)d_in[0];
    const float* det_boxes   = (const float*)d_in[1];
    const float* track_pts   = (const float*)d_in[2];
    const float* track_boxes = (const float*)d_in[3];
    const int*   adj         = (const int*)d_in[4];
    const float* pn_w1 = (const float*)d_in[5],  *pn_b1 = (const float*)d_in[6];
    const float* pn_w2 = (const float*)d_in[7],  *pn_b2 = (const float*)d_in[8];
    const float* pn_w3 = (const float*)d_in[9],  *pn_b3 = (const float*)d_in[10];
    const float* dm_w1 = (const float*)d_in[11], *dm_b1 = (const float*)d_in[12];
    const float* dm_w2 = (const float*)d_in[13], *dm_b2 = (const float*)d_in[14];
    const float* l0_wih = (const float*)d_in[15], *l0_whh = (const float*)d_in[16];
    const float* l0_bih = (const float*)d_in[17], *l0_bhh = (const float*)d_in[18];
    const float* l1_wih = (const float*)d_in[19], *l1_whh = (const float*)d_in[20];
    const float* l1_bih = (const float*)d_in[21], *l1_bhh = (const float*)d_in[22];
    const float* gc_wt = (const float*)d_in[23], *gc_bt = (const float*)d_in[24];
    const float* gc_wp = (const float*)d_in[25], *gc_bp = (const float*)d_in[26];
    const float* er_w1 = (const float*)d_in[27], *er_b1 = (const float*)d_in[28];
    const float* er_w2 = (const float*)d_in[29], *er_b2 = (const float*)d_in[30];
    float* out = (float*)d_out;

    float* hA  = (float*)d_ws;           // [512][128]
    float* Th  = hA  + NV * 128;         // [512][128]
    float* Ph  = Th  + NV * 128;         // [512][128]
    float* Th2 = Ph  + NV * 128;         // [512][128]
    float* Ph2 = Th2 + NV * 128;         // [512][128]
    float* uu1 = Ph2 + NV * 128;         // [256][64]
    float* uu2 = uu1 + NDET * 64;        // [256][64]

    pointnet_kernel<<<NV, 256, 0, stream>>>(det_pts, track_pts,
        pn_w1, pn_b1, pn_w2, pn_b2, pn_w3, pn_b3,
        det_boxes, dm_w1, dm_b1, dm_w2, dm_b2, hA);
    lstm_kernel<<<NTRK, 256, 0, stream>>>(track_boxes,
        l0_wih, l0_whh, l0_bih, l0_bhh, l1_wih, l1_whh, l1_bih, l1_bhh, hA);

    // layer-0 GEMM from hA
    econv_gemm_kernel<<<NV, 128, 0, stream>>>(hA,
        gc_wt, gc_wp, gc_bp, Th, Ph);

    const size_t WSZ = 128 * 128;
    // k=0: max + layer-1 GEMM + uproj(aff1)
    econv_fused_kernel<<<NV, 128, 0, stream>>>(adj, Th, Ph, gc_bt,
        gc_wt + WSZ, gc_wp + WSZ, gc_bp + 128, er_w1, uu1, Th2, Ph2);
    // k=1: max + layer-2 GEMM
    econv_fused_kernel<<<NV, 128, 0, stream>>>(adj, Th2, Ph2, gc_bt + 128,
        gc_wt + 2 * WSZ, gc_wp + 2 * WSZ, gc_bp + 256, nullptr, nullptr, Th, Ph);
    // k=2: max + layer-3 GEMM
    econv_fused_kernel<<<NV, 128, 0, stream>>>(adj, Th, Ph, gc_bt + 256,
        gc_wt + 3 * WSZ, gc_wp + 3 * WSZ, gc_bp + 384, nullptr, nullptr, Th2, Ph2);
    // k=3: max + uproj(aff_final)
    econv_fused_kernel<<<NV, 128, 0, stream>>>(adj, Th2, Ph2, gc_bt + 384,
        nullptr, nullptr, nullptr, er_w1, uu2, nullptr, nullptr);

    edge_kernel<<<NDET, 256, 0, stream>>>(uu1, er_b1, er_w2, er_b2, out);
    edge_kernel<<<NDET, 256, 0, stream>>>(uu2, er_b1, er_w2, er_b2, out + NDET * NTRK);
}